// Round 2
// baseline (7026.530 us; speedup 1.0000x reference)
//
#include <hip/hip_runtime.h>

// Problem constants
#define NB   4       // batch
#define CC   192     // d_model
#define LL   4096    // H*W
#define DI   384     // d_inner
#define DST  16      // d_state
#define DTR  12      // dt_rank
#define NSEQ 16      // 4 dirs * 4 batch
#define NTOK 16384   // NB*LL

__device__ __forceinline__ float siluf(float x) {
    return x / (1.f + __expf(-x));
}

// scan-position l -> hmod position p, per direction
__device__ __forceinline__ int perm_pos(int dir, int l) {
    if (dir == 0) return l;
    if (dir == 1) return 4095 - l;
    if (dir == 2) return ((l & 63) << 6) | (l >> 6);
    int m = 4095 - l;
    return ((m & 63) << 6) | (m >> 6);
}

// K1: mods = silu(c) @ adaln_w + adaln_b   (4 x 1152)
__global__ void k_mods(const float* __restrict__ c, const float* __restrict__ w,
                       const float* __restrict__ bias, float* __restrict__ mods) {
    int idx = blockIdx.x * 256 + threadIdx.x;
    if (idx >= NB * 1152) return;
    int n = idx / 1152, j = idx % 1152;
    float acc = bias[j];
    for (int k = 0; k < CC; ++k) {
        acc = fmaf(siluf(c[n * CC + k]), w[k * 1152 + j], acc);
    }
    mods[idx] = acc;
}

// K2: hmod = modulate(LN(tokens), sh1, sc1); tokens read straight from x layout
__global__ void k_ln_mod(const float* __restrict__ x, const float* __restrict__ mods,
                         float* __restrict__ hmod) {
    int wave = blockIdx.x * 4 + (threadIdx.x >> 6);   // 16384 waves, one per token
    int lane = threadIdx.x & 63;
    int b = wave >> 12;
    int p = wave & 4095;
    float v0 = x[((size_t)(b * CC + lane) * LL) + p];
    float v1 = x[((size_t)(b * CC + lane + 64) * LL) + p];
    float v2 = x[((size_t)(b * CC + lane + 128) * LL) + p];
    float s = v0 + v1 + v2, sq = v0 * v0 + v1 * v1 + v2 * v2;
    #pragma unroll
    for (int o = 1; o < 64; o <<= 1) { s += __shfl_xor(s, o); sq += __shfl_xor(sq, o); }
    float mu = s * (1.f / 192.f);
    float var = sq * (1.f / 192.f) - mu * mu;
    float rs = rsqrtf(var + 1e-6f);
    const float* mb = mods + b * 1152;
    size_t base = ((size_t)(b * LL + p)) * CC;
    int c0 = lane, c1 = lane + 64, c2 = lane + 128;
    hmod[base + c0] = (v0 - mu) * rs * (1.f + mb[192 + c0]) + mb[c0];
    hmod[base + c1] = (v1 - mu) * rs * (1.f + mb[192 + c1]) + mb[c1];
    hmod[base + c2] = (v2 - mu) * rs * (1.f + mb[192 + c2]) + mb[c2];
}

// K3: xz = hmod @ W_in + b_in  (direction-0 layout only; other dirs are permutations)
__global__ void k_xz(const float* __restrict__ hmod, const float* __restrict__ W_in,
                     const float* __restrict__ b_in, float* __restrict__ xz) {
    __shared__ float hs[CC];
    int tok = blockIdx.x;            // 16384
    int t = threadIdx.x;             // 256
    const float* hrow = hmod + (size_t)tok * CC;
    if (t < CC) hs[t] = hrow[t];
    __syncthreads();
    float acc[3];
    #pragma unroll
    for (int r = 0; r < 3; ++r) acc[r] = b_in[t + 256 * r];
    for (int k = 0; k < CC; ++k) {
        float hv = hs[k];
        const float* wr = W_in + k * 768;
        #pragma unroll
        for (int r = 0; r < 3; ++r) acc[r] = fmaf(hv, wr[t + 256 * r], acc[r]);
    }
    float* orow = xz + (size_t)tok * 768;
    #pragma unroll
    for (int r = 0; r < 3; ++r) orow[t + 256 * r] = acc[r];
}

// K4: per (seq,l): causal conv(+silu) -> xc (shared only); dbl[44] = xc@W_x, stored stride-48
__global__ void k_conv_dbl(const float* __restrict__ xz, const float* __restrict__ conv_w,
                           const float* __restrict__ conv_b, const float* __restrict__ W_x,
                           float* __restrict__ dbl48) {
    __shared__ float xcs[DI];
    __shared__ float red[352];
    int blk = blockIdx.x;            // 65536 = seq*4096 + l
    int seq = blk >> 12;
    int l = blk & 4095;
    int dir = seq >> 2, b = seq & 3;
    int t = threadIdx.x;             // 384
    // phase 1: conv + silu
    {
        float acc = conv_b[t];
        #pragma unroll
        for (int k = 0; k < 4; ++k) {
            int lk = l - 3 + k;
            if (lk >= 0) {
                int p = perm_pos(dir, lk);
                acc = fmaf(xz[((size_t)(b * LL + p)) * 768 + t], conv_w[t * 4 + k], acc);
            }
        }
        xcs[t] = siluf(acc);
    }
    __syncthreads();
    // phase 2: dbl[44] = xcs @ W_x  (44 outputs x 8 partial threads)
    if (t < 352) {
        int j = t >> 3, i = t & 7;
        float ps = 0.f;
        int k0 = i * 48;
        #pragma unroll 8
        for (int kk = 0; kk < 48; ++kk)
            ps = fmaf(xcs[k0 + kk], W_x[(k0 + kk) * 44 + j], ps);
        red[t] = ps;
    }
    __syncthreads();
    if (t < 44) {
        float sum = 0.f;
        #pragma unroll
        for (int i = 0; i < 8; ++i) sum += red[t * 8 + i];
        dbl48[((size_t)blk) * 48 + t] = sum;   // [0:12)=dt-rank, [12:28)=B, [28:44)=C
    }
}

// K5: selective scan, fully fused. One wave per (seq, 4 channels); 16 lanes = 16 states.
// Recomputes conv via register sliding window, dt via preloaded W_dt column.
// atomicAdd 0.25*y*silu(z) into ysum[(b,p,d)].
__global__ void k_scan(const float* __restrict__ xz, const float* __restrict__ dbl48,
                       const float* __restrict__ conv_w, const float* __restrict__ conv_b,
                       const float* __restrict__ W_dt, const float* __restrict__ b_dt,
                       const float* __restrict__ A_log, const float* __restrict__ Dp,
                       float* __restrict__ ysum) {
    int blk = blockIdx.x;            // 1536 = seq*96 + grp
    int seq = blk / 96;
    int dbase = (blk % 96) * 4;
    int lane = threadIdx.x;          // 64
    int s = lane & 15, g = lane >> 4;
    int d = dbase + g;
    int dir = seq >> 2, b = seq & 3;
    float A_ls = -__expf(A_log[d * DST + s]);
    float D_d = Dp[d];
    float bdt = b_dt[d];
    float wdt[DTR];
    #pragma unroll
    for (int r = 0; r < DTR; ++r) wdt[r] = W_dt[r * DI + d];
    float cw0 = conv_w[d * 4 + 0], cw1 = conv_w[d * 4 + 1];
    float cw2 = conv_w[d * 4 + 2], cw3 = conv_w[d * 4 + 3];
    float cb = conv_b[d];
    const float* dblp = dbl48 + (size_t)seq * LL * 48;
    const float* xp = xz + (size_t)b * LL * 768;       // x part: [p*768 + d]
    const float* zp = xp + DI;                          // z part: [p*768 + d]
    float* yb = ysum + (size_t)b * LL * DI;
    float h = 0.f;
    float xm3 = 0.f, xm2 = 0.f, xm1 = 0.f;              // conv window (raw x inputs)
    #pragma unroll 4
    for (int l = 0; l < LL; ++l) {
        int p = perm_pos(dir, l);
        float xcur = xp[(size_t)p * 768 + d];           // broadcast across 16 lanes
        float conv = cb;
        conv = fmaf(cw0, xm3, conv);
        conv = fmaf(cw1, xm2, conv);
        conv = fmaf(cw2, xm1, conv);
        conv = fmaf(cw3, xcur, conv);
        float xv = siluf(conv);
        const float* dr = dblp + l * 48;
        float acc = bdt;
        #pragma unroll
        for (int r = 0; r < DTR; ++r) acc = fmaf(dr[r], wdt[r], acc);
        float dtv = (acc > 20.f) ? acc : log1pf(__expf(acc));
        float Bv = dr[12 + s];
        float Cv = dr[28 + s];
        float dA = __expf(dtv * A_ls);
        h = fmaf(h, dA, dtv * xv * Bv);
        float pr = h * Cv;
        pr += __shfl_xor(pr, 1);
        pr += __shfl_xor(pr, 2);
        pr += __shfl_xor(pr, 4);
        pr += __shfl_xor(pr, 8);
        if (s == 0) {
            float y = pr + D_d * xv;
            float zv = zp[(size_t)p * 768 + d];
            atomicAdd(&yb[(size_t)p * DI + d], 0.25f * y * siluf(zv));
        }
        xm3 = xm2; xm2 = xm1; xm1 = xcur;
    }
}

// K6: ysum @ W_out, +b_out, residual with g1 -> tok2
__global__ void k_out_gemm(const float* __restrict__ ysum, const float* __restrict__ W_out,
                           const float* __restrict__ b_out, const float* __restrict__ x,
                           const float* __restrict__ mods, float* __restrict__ tok2) {
    __shared__ float ys[DI];
    int blk = blockIdx.x;            // 16384 = b*4096 + p
    int b = blk >> 12, p = blk & 4095;
    int t = threadIdx.x;             // 192
    for (int dd = t; dd < DI; dd += 192) ys[dd] = ysum[(size_t)blk * DI + dd];
    __syncthreads();
    float acc = 0.f;
    for (int k = 0; k < DI; ++k) acc = fmaf(ys[k], W_out[k * CC + t], acc);
    float o = acc + b_out[t];        // 0.25 already applied in scan
    float tok = x[((size_t)(b * CC + t)) * LL + p];
    float g1 = mods[b * 1152 + 384 + t];
    tok2[((size_t)blk) * CC + t] = tok + g1 * o;
}

// K7: m = modulate(LN(tok2), sh2, sc2); a1 = gelu(m @ w1 + b1)
__global__ void k_mlp1(const float* __restrict__ tok2, const float* __restrict__ mods,
                       const float* __restrict__ w1, const float* __restrict__ b1,
                       float* __restrict__ a1) {
    __shared__ float m[CC];
    __shared__ float wsum[4], wsq[4];
    int blk = blockIdx.x;            // 16384
    int b = blk >> 12;
    int t = threadIdx.x;             // 256
    float v = 0.f;
    if (t < CC) v = tok2[(size_t)blk * CC + t];
    float s = v, sq = v * v;
    #pragma unroll
    for (int o = 1; o < 64; o <<= 1) { s += __shfl_xor(s, o); sq += __shfl_xor(sq, o); }
    if ((t & 63) == 0) { wsum[t >> 6] = s; wsq[t >> 6] = sq; }
    __syncthreads();
    float tots = wsum[0] + wsum[1] + wsum[2] + wsum[3];
    float totq = wsq[0] + wsq[1] + wsq[2] + wsq[3];
    float mu = tots * (1.f / 192.f);
    float var = totq * (1.f / 192.f) - mu * mu;
    float rs = rsqrtf(var + 1e-6f);
    if (t < CC) {
        const float* mb = mods + b * 1152;
        m[t] = (v - mu) * rs * (1.f + mb[768 + t]) + mb[576 + t];
    }
    __syncthreads();
    float acc[3];
    #pragma unroll
    for (int r = 0; r < 3; ++r) acc[r] = b1[t + 256 * r];
    for (int k = 0; k < CC; ++k) {
        float mv = m[k];
        #pragma unroll
        for (int r = 0; r < 3; ++r) acc[r] = fmaf(mv, w1[k * 768 + t + 256 * r], acc[r]);
    }
    float* orow = a1 + (size_t)blk * 768;
    #pragma unroll
    for (int r = 0; r < 3; ++r) {
        float u = acc[r];
        float inner = 0.7978845608028654f * (u + 0.044715f * u * u * u);
        float e = __expf(2.f * inner);
        float th = 1.f - 2.f / (e + 1.f);   // stable tanh
        orow[t + 256 * r] = 0.5f * u * (1.f + th);
    }
}

// K8: out = tok2 + g2 * (a1 @ w2 + b2), written back in (b, C, h, w) layout
__global__ void k_mlp2(const float* __restrict__ a1, const float* __restrict__ tok2,
                       const float* __restrict__ mods, const float* __restrict__ w2,
                       const float* __restrict__ b2, float* __restrict__ out) {
    __shared__ float as[768];
    int blk = blockIdx.x;            // 16384
    int b = blk >> 12, p = blk & 4095;
    int t = threadIdx.x;             // 192
    const float* arow = a1 + (size_t)blk * 768;
    for (int k = t; k < 768; k += 192) as[k] = arow[k];
    __syncthreads();
    float acc = b2[t];
    for (int k = 0; k < 768; ++k) acc = fmaf(as[k], w2[k * CC + t], acc);
    float g2 = mods[b * 1152 + 960 + t];
    float o = tok2[(size_t)blk * CC + t] + g2 * acc;
    out[((size_t)(b * CC + t)) * LL + p] = o;
}

extern "C" void kernel_launch(void* const* d_in, const int* in_sizes, int n_in,
                              void* d_out, int out_size, void* d_ws, size_t ws_size,
                              hipStream_t stream) {
    const float* x       = (const float*)d_in[0];
    const float* c       = (const float*)d_in[1];
    const float* adaln_w = (const float*)d_in[2];
    const float* adaln_b = (const float*)d_in[3];
    const float* W_in    = (const float*)d_in[4];
    const float* b_in    = (const float*)d_in[5];
    const float* conv_w  = (const float*)d_in[6];
    const float* conv_b  = (const float*)d_in[7];
    const float* W_x     = (const float*)d_in[8];
    const float* W_dt    = (const float*)d_in[9];
    const float* b_dt    = (const float*)d_in[10];
    const float* A_log   = (const float*)d_in[11];
    const float* Dp      = (const float*)d_in[12];
    const float* W_out   = (const float*)d_in[13];
    const float* b_out   = (const float*)d_in[14];
    const float* w1      = (const float*)d_in[15];
    const float* b1      = (const float*)d_in[16];
    const float* w2      = (const float*)d_in[17];
    const float* b2      = (const float*)d_in[18];

    // workspace layout (f32 elements), total ~96 MB
    float* ws   = (float*)d_ws;
    float* mods = ws;                          // 4,608
    float* hmod = ws + 4608;                   // 3,145,728   (reused as tok2)
    float* xz   = hmod + 3145728;              // 12,582,912  (reused as a1)
    float* dbl  = xz + 12582912;               // 3,145,728   (44 vals/token, stride 48)
    float* ysum = dbl + 3145728;               // 6,291,456   (direction-summed y*silu(z))
    float* out  = (float*)d_out;

    hipMemsetAsync(ysum, 0, (size_t)6291456 * sizeof(float), stream);
    k_mods<<<18, 256, 0, stream>>>(c, adaln_w, adaln_b, mods);
    k_ln_mod<<<4096, 256, 0, stream>>>(x, mods, hmod);
    k_xz<<<16384, 256, 0, stream>>>(hmod, W_in, b_in, xz);
    k_conv_dbl<<<65536, 384, 0, stream>>>(xz, conv_w, conv_b, W_x, dbl);
    k_scan<<<1536, 64, 0, stream>>>(xz, dbl, conv_w, conv_b, W_dt, b_dt, A_log, Dp, ysum);
    k_out_gemm<<<16384, 192, 0, stream>>>(ysum, W_out, b_out, x, mods, hmod);
    k_mlp1<<<16384, 256, 0, stream>>>(hmod, mods, w1, b1, xz);
    k_mlp2<<<16384, 192, 0, stream>>>(xz, hmod, mods, w2, b2, out);
}

// Round 3
// 5639.342 us; speedup vs baseline: 1.2460x; 1.2460x over previous
//
#include <hip/hip_runtime.h>
#include <hip/hip_bf16.h>

// Problem constants
#define NB   4       // batch
#define CC   192     // d_model
#define LL   4096    // H*W
#define DI   384     // d_inner
#define DST  16      // d_state
#define DTR  12      // dt_rank
#define NSEQ 16      // 4 dirs * 4 batch
#define NTOK 16384   // NB*LL

__device__ __forceinline__ float siluf(float x) {
    return x / (1.f + __expf(-x));
}

// scan-position l -> hmod position p, per direction
__device__ __forceinline__ int perm_pos(int dir, int l) {
    if (dir == 0) return l;
    if (dir == 1) return 4095 - l;
    if (dir == 2) return ((l & 63) << 6) | (l >> 6);
    int m = 4095 - l;
    return ((m & 63) << 6) | (m >> 6);
}

// K1: mods = silu(c) @ adaln_w + adaln_b   (4 x 1152)
__global__ void k_mods(const float* __restrict__ c, const float* __restrict__ w,
                       const float* __restrict__ bias, float* __restrict__ mods) {
    int idx = blockIdx.x * 256 + threadIdx.x;
    if (idx >= NB * 1152) return;
    int n = idx / 1152, j = idx % 1152;
    float acc = bias[j];
    for (int k = 0; k < CC; ++k) {
        acc = fmaf(siluf(c[n * CC + k]), w[k * 1152 + j], acc);
    }
    mods[idx] = acc;
}

// K2: hmod = modulate(LN(tokens), sh1, sc1); tokens read straight from x layout
__global__ void k_ln_mod(const float* __restrict__ x, const float* __restrict__ mods,
                         float* __restrict__ hmod) {
    int wave = blockIdx.x * 4 + (threadIdx.x >> 6);   // 16384 waves, one per token
    int lane = threadIdx.x & 63;
    int b = wave >> 12;
    int p = wave & 4095;
    float v0 = x[((size_t)(b * CC + lane) * LL) + p];
    float v1 = x[((size_t)(b * CC + lane + 64) * LL) + p];
    float v2 = x[((size_t)(b * CC + lane + 128) * LL) + p];
    float s = v0 + v1 + v2, sq = v0 * v0 + v1 * v1 + v2 * v2;
    #pragma unroll
    for (int o = 1; o < 64; o <<= 1) { s += __shfl_xor(s, o); sq += __shfl_xor(sq, o); }
    float mu = s * (1.f / 192.f);
    float var = sq * (1.f / 192.f) - mu * mu;
    float rs = rsqrtf(var + 1e-6f);
    const float* mb = mods + b * 1152;
    size_t base = ((size_t)(b * LL + p)) * CC;
    int c0 = lane, c1 = lane + 64, c2 = lane + 128;
    hmod[base + c0] = (v0 - mu) * rs * (1.f + mb[192 + c0]) + mb[c0];
    hmod[base + c1] = (v1 - mu) * rs * (1.f + mb[192 + c1]) + mb[c1];
    hmod[base + c2] = (v2 - mu) * rs * (1.f + mb[192 + c2]) + mb[c2];
}

// K3: xz = hmod @ W_in + b_in  (direction-0 layout only; other dirs are permutations)
__global__ void k_xz(const float* __restrict__ hmod, const float* __restrict__ W_in,
                     const float* __restrict__ b_in, float* __restrict__ xz) {
    __shared__ float hs[CC];
    int tok = blockIdx.x;            // 16384
    int t = threadIdx.x;             // 256
    const float* hrow = hmod + (size_t)tok * CC;
    if (t < CC) hs[t] = hrow[t];
    __syncthreads();
    float acc[3];
    #pragma unroll
    for (int r = 0; r < 3; ++r) acc[r] = b_in[t + 256 * r];
    for (int k = 0; k < CC; ++k) {
        float hv = hs[k];
        const float* wr = W_in + k * 768;
        #pragma unroll
        for (int r = 0; r < 3; ++r) acc[r] = fmaf(hv, wr[t + 256 * r], acc[r]);
    }
    float* orow = xz + (size_t)tok * 768;
    #pragma unroll
    for (int r = 0; r < 3; ++r) orow[t + 256 * r] = acc[r];
}

// K4: per (seq,l): conv+silu -> xv; dbl44 = xv@W_x (-> dbl48 store);
// dtv = softplus(dbl[:12]@W_dt + b_dt); store dtv, dtx=dtv*xv (bf16);
// for dir0 also store zs = 0.25*silu(z) (bf16).
__global__ void k_conv_dbl(const float* __restrict__ xz, const float* __restrict__ conv_w,
                           const float* __restrict__ conv_b, const float* __restrict__ W_x,
                           const float* __restrict__ W_dt, const float* __restrict__ b_dt,
                           float* __restrict__ dbl48,
                           __hip_bfloat16* __restrict__ dtv_a,
                           __hip_bfloat16* __restrict__ dtx_a,
                           __hip_bfloat16* __restrict__ zs_a) {
    __shared__ float xcs[DI];
    __shared__ float red[352];
    __shared__ float dbls[DTR];
    int blk = blockIdx.x;            // 65536 = seq*4096 + l
    int seq = blk >> 12;
    int l = blk & 4095;
    int dir = seq >> 2, b = seq & 3;
    int t = threadIdx.x;             // 384
    // phase 1: conv + silu
    float xv;
    {
        float acc = conv_b[t];
        #pragma unroll
        for (int k = 0; k < 4; ++k) {
            int lk = l - 3 + k;
            if (lk >= 0) {
                int p = perm_pos(dir, lk);
                acc = fmaf(xz[((size_t)(b * LL + p)) * 768 + t], conv_w[t * 4 + k], acc);
            }
        }
        xv = siluf(acc);
        xcs[t] = xv;
    }
    __syncthreads();
    // phase 2: dbl[44] = xcs @ W_x  (44 outputs x 8 partial threads)
    if (t < 352) {
        int j = t >> 3, i = t & 7;
        float ps = 0.f;
        int k0 = i * 48;
        #pragma unroll 8
        for (int kk = 0; kk < 48; ++kk)
            ps = fmaf(xcs[k0 + kk], W_x[(k0 + kk) * 44 + j], ps);
        red[t] = ps;
    }
    __syncthreads();
    if (t < 44) {
        float sum = 0.f;
        #pragma unroll
        for (int i = 0; i < 8; ++i) sum += red[t * 8 + i];
        if (t < DTR) dbls[t] = sum;
        dbl48[((size_t)blk) * 48 + t] = sum;   // [0:12)=dt-rank, [12:28)=B, [28:44)=C
    }
    __syncthreads();
    // phase 3: dt = softplus(dbls[0:12] @ W_dt[:,t] + b_dt[t]); store dtv, dtx
    {
        float acc = b_dt[t];
        #pragma unroll
        for (int r = 0; r < DTR; ++r) acc = fmaf(dbls[r], W_dt[r * DI + t], acc);
        float sp = (acc > 15.f) ? acc : __logf(1.f + __expf(acc));
        sp = fmaxf(sp, 1e-12f);                 // avoid 0*inf in scan's xv recovery
        size_t o = (size_t)blk * DI + t;
        dtv_a[o] = __float2bfloat16(sp);
        dtx_a[o] = __float2bfloat16(sp * xv);
        if (seq < 4) {                          // dir 0: p == l
            float zvv = xz[((size_t)(b * LL + l)) * 768 + DI + t];
            zs_a[((size_t)(b * LL + l)) * DI + t] = __float2bfloat16(0.25f * siluf(zvv));
        }
    }
}

// K5: selective scan, slim. One wave per (seq, 4 channels); 16 lanes = 16 states.
// atomicAdd zs*(pr + D*xv) into ysum[(b,p,d)].
__global__ void k_scan(const __hip_bfloat16* __restrict__ dtv_a,
                       const __hip_bfloat16* __restrict__ dtx_a,
                       const float* __restrict__ dbl48,
                       const __hip_bfloat16* __restrict__ zs_a,
                       const float* __restrict__ A_log, const float* __restrict__ Dp,
                       float* __restrict__ ysum) {
    int blk = blockIdx.x;            // 1536 = seq*96 + grp
    int seq = blk / 96;
    int dbase = (blk % 96) * 4;
    int lane = threadIdx.x;          // 64
    int s = lane & 15, g = lane >> 4;
    int d = dbase + g;
    int dir = seq >> 2, b = seq & 3;
    float a_s = -__expf(A_log[d * DST + s]);
    float D_d = Dp[d];
    const __hip_bfloat16* pdtv = dtv_a + (size_t)seq * LL * DI + d;
    const __hip_bfloat16* pdtx = dtx_a + (size_t)seq * LL * DI + d;
    const float* dr = dbl48 + (size_t)seq * LL * 48;
    const __hip_bfloat16* zsp = zs_a + (size_t)b * LL * DI + d;
    float* yb = ysum + (size_t)b * LL * DI + d;
    float h = 0.f;
    #pragma unroll 8
    for (int l = 0; l < LL; ++l) {
        float dtvf = __bfloat162float(pdtv[(size_t)l * DI]);
        float dtxf = __bfloat162float(pdtx[(size_t)l * DI]);
        float Bv = dr[l * 48 + 12 + s];
        float Cv = dr[l * 48 + 28 + s];
        float dA = __expf(dtvf * a_s);
        h = fmaf(h, dA, dtxf * Bv);
        float pr = h * Cv;
        pr += __shfl_xor(pr, 1);
        pr += __shfl_xor(pr, 2);
        pr += __shfl_xor(pr, 4);
        pr += __shfl_xor(pr, 8);
        if (s == 0) {
            float xv = dtxf * __builtin_amdgcn_rcpf(dtvf);
            float y = pr + D_d * xv;
            int p = perm_pos(dir, l);
            float zsv = __bfloat162float(zsp[(size_t)p * DI]);
            atomicAdd(&yb[(size_t)p * DI], zsv * y);
        }
    }
}

// K6: ysum @ W_out, +b_out, residual with g1 -> tok2
__global__ void k_out_gemm(const float* __restrict__ ysum, const float* __restrict__ W_out,
                           const float* __restrict__ b_out, const float* __restrict__ x,
                           const float* __restrict__ mods, float* __restrict__ tok2) {
    __shared__ float ys[DI];
    int blk = blockIdx.x;            // 16384 = b*4096 + p
    int b = blk >> 12, p = blk & 4095;
    int t = threadIdx.x;             // 192
    for (int dd = t; dd < DI; dd += 192) ys[dd] = ysum[(size_t)blk * DI + dd];
    __syncthreads();
    float acc = 0.f;
    for (int k = 0; k < DI; ++k) acc = fmaf(ys[k], W_out[k * CC + t], acc);
    float o = acc + b_out[t];        // 0.25 & silu(z) already applied upstream
    float tok = x[((size_t)(b * CC + t)) * LL + p];
    float g1 = mods[b * 1152 + 384 + t];
    tok2[((size_t)blk) * CC + t] = tok + g1 * o;
}

// K7: m = modulate(LN(tok2), sh2, sc2); a1 = gelu(m @ w1 + b1)
__global__ void k_mlp1(const float* __restrict__ tok2, const float* __restrict__ mods,
                       const float* __restrict__ w1, const float* __restrict__ b1,
                       float* __restrict__ a1) {
    __shared__ float m[CC];
    __shared__ float wsum[4], wsq[4];
    int blk = blockIdx.x;            // 16384
    int b = blk >> 12;
    int t = threadIdx.x;             // 256
    float v = 0.f;
    if (t < CC) v = tok2[(size_t)blk * CC + t];
    float s = v, sq = v * v;
    #pragma unroll
    for (int o = 1; o < 64; o <<= 1) { s += __shfl_xor(s, o); sq += __shfl_xor(sq, o); }
    if ((t & 63) == 0) { wsum[t >> 6] = s; wsq[t >> 6] = sq; }
    __syncthreads();
    float tots = wsum[0] + wsum[1] + wsum[2] + wsum[3];
    float totq = wsq[0] + wsq[1] + wsq[2] + wsq[3];
    float mu = tots * (1.f / 192.f);
    float var = totq * (1.f / 192.f) - mu * mu;
    float rs = rsqrtf(var + 1e-6f);
    if (t < CC) {
        const float* mb = mods + b * 1152;
        m[t] = (v - mu) * rs * (1.f + mb[768 + t]) + mb[576 + t];
    }
    __syncthreads();
    float acc[3];
    #pragma unroll
    for (int r = 0; r < 3; ++r) acc[r] = b1[t + 256 * r];
    for (int k = 0; k < CC; ++k) {
        float mv = m[k];
        #pragma unroll
        for (int r = 0; r < 3; ++r) acc[r] = fmaf(mv, w1[k * 768 + t + 256 * r], acc[r]);
    }
    float* orow = a1 + (size_t)blk * 768;
    #pragma unroll
    for (int r = 0; r < 3; ++r) {
        float u = acc[r];
        float inner = 0.7978845608028654f * (u + 0.044715f * u * u * u);
        float e = __expf(2.f * inner);
        float th = 1.f - 2.f / (e + 1.f);   // stable tanh
        orow[t + 256 * r] = 0.5f * u * (1.f + th);
    }
}

// K8: out = tok2 + g2 * (a1 @ w2 + b2), written back in (b, C, h, w) layout
__global__ void k_mlp2(const float* __restrict__ a1, const float* __restrict__ tok2,
                       const float* __restrict__ mods, const float* __restrict__ w2,
                       const float* __restrict__ b2, float* __restrict__ out) {
    __shared__ float as[768];
    int blk = blockIdx.x;            // 16384
    int b = blk >> 12, p = blk & 4095;
    int t = threadIdx.x;             // 192
    const float* arow = a1 + (size_t)blk * 768;
    for (int k = t; k < 768; k += 192) as[k] = arow[k];
    __syncthreads();
    float acc = b2[t];
    for (int k = 0; k < 768; ++k) acc = fmaf(as[k], w2[k * CC + t], acc);
    float g2 = mods[b * 1152 + 960 + t];
    float o = tok2[(size_t)blk * CC + t] + g2 * acc;
    out[((size_t)(b * CC + t)) * LL + p] = o;
}

extern "C" void kernel_launch(void* const* d_in, const int* in_sizes, int n_in,
                              void* d_out, int out_size, void* d_ws, size_t ws_size,
                              hipStream_t stream) {
    const float* x       = (const float*)d_in[0];
    const float* c       = (const float*)d_in[1];
    const float* adaln_w = (const float*)d_in[2];
    const float* adaln_b = (const float*)d_in[3];
    const float* W_in    = (const float*)d_in[4];
    const float* b_in    = (const float*)d_in[5];
    const float* conv_w  = (const float*)d_in[6];
    const float* conv_b  = (const float*)d_in[7];
    const float* W_x     = (const float*)d_in[8];
    const float* W_dt    = (const float*)d_in[9];
    const float* b_dt    = (const float*)d_in[10];
    const float* A_log   = (const float*)d_in[11];
    const float* Dp      = (const float*)d_in[12];
    const float* W_out   = (const float*)d_in[13];
    const float* b_out   = (const float*)d_in[14];
    const float* w1      = (const float*)d_in[15];
    const float* b1      = (const float*)d_in[16];
    const float* w2      = (const float*)d_in[17];
    const float* b2      = (const float*)d_in[18];

    // workspace (~176 MB) with time-aliased regions:
    //  region B (3,145,728 f32): hmod (k2-k3) -> dbl48 (k4-k5) -> tok2 (k6-k8)
    //  region C (12,582,912 f32): xz (k3-k4) -> ysum (k5-k6, first 6.3M) -> a1 (k7-k8)
    float* ws = (float*)d_ws;
    float* mods = ws;                               // 4,608
    float* regB = ws + 4608;                        // 3,145,728
    float* regC = regB + 3145728;                   // 12,582,912
    __hip_bfloat16* dtv_a = (__hip_bfloat16*)(regC + 12582912);  // 25,165,824 bf16
    __hip_bfloat16* dtx_a = dtv_a + 25165824;                    // 25,165,824 bf16
    __hip_bfloat16* zs_a  = dtx_a + 25165824;                    // 6,291,456 bf16
    float* out = (float*)d_out;

    float* hmod  = regB;
    float* dbl48 = regB;
    float* tok2  = regB;
    float* xz    = regC;
    float* ysum  = regC;
    float* a1    = regC;

    k_mods<<<18, 256, 0, stream>>>(c, adaln_w, adaln_b, mods);
    k_ln_mod<<<4096, 256, 0, stream>>>(x, mods, hmod);
    k_xz<<<16384, 256, 0, stream>>>(hmod, W_in, b_in, xz);
    k_conv_dbl<<<65536, 384, 0, stream>>>(xz, conv_w, conv_b, W_x, W_dt, b_dt,
                                          dbl48, dtv_a, dtx_a, zs_a);
    hipMemsetAsync(ysum, 0, (size_t)6291456 * sizeof(float), stream);
    k_scan<<<1536, 64, 0, stream>>>(dtv_a, dtx_a, dbl48, zs_a, A_log, Dp, ysum);
    k_out_gemm<<<16384, 192, 0, stream>>>(ysum, W_out, b_out, x, mods, tok2);
    k_mlp1<<<16384, 256, 0, stream>>>(tok2, mods, w1, b1, a1);
    k_mlp2<<<16384, 192, 0, stream>>>(a1, tok2, mods, w2, b2, out);
}

// Round 4
// 2494.160 us; speedup vs baseline: 2.8172x; 2.2610x over previous
//
#include <hip/hip_runtime.h>
#include <hip/hip_bf16.h>

// Problem constants
#define NB   4       // batch
#define CC   192     // d_model
#define LL   4096    // H*W
#define DI   384     // d_inner
#define DST  16      // d_state
#define DTR  12      // dt_rank
#define NC   32      // scan chunks
#define CL   128     // chunk length

typedef unsigned int uint32;
typedef unsigned short ushort16;

__device__ __forceinline__ float siluf(float x) {
    return x / (1.f + __expf(-x));
}
__device__ __forceinline__ float bf16lo(uint32 u) { return __uint_as_float(u << 16); }
__device__ __forceinline__ float bf16hi(uint32 u) { return __uint_as_float(u & 0xffff0000u); }

// scan-position l -> token position p, per direction
__device__ __forceinline__ int perm_pos(int dir, int l) {
    if (dir == 0) return l;
    if (dir == 1) return 4095 - l;
    if (dir == 2) return ((l & 63) << 6) | (l >> 6);
    int m = 4095 - l;
    return ((m & 63) << 6) | (m >> 6);
}

// K1: mods = silu(c) @ adaln_w + adaln_b   (4 x 1152)
__global__ void k_mods(const float* __restrict__ c, const float* __restrict__ w,
                       const float* __restrict__ bias, float* __restrict__ mods) {
    int idx = blockIdx.x * 256 + threadIdx.x;
    if (idx >= NB * 1152) return;
    int n = idx / 1152, j = idx % 1152;
    float acc = bias[j];
    for (int k = 0; k < CC; ++k) {
        acc = fmaf(siluf(c[n * CC + k]), w[k * 1152 + j], acc);
    }
    mods[idx] = acc;
}

// K2: hmod = modulate(LN(tokens), sh1, sc1)
__global__ void k_ln_mod(const float* __restrict__ x, const float* __restrict__ mods,
                         float* __restrict__ hmod) {
    int wave = blockIdx.x * 4 + (threadIdx.x >> 6);
    int lane = threadIdx.x & 63;
    int b = wave >> 12;
    int p = wave & 4095;
    float v0 = x[((size_t)(b * CC + lane) * LL) + p];
    float v1 = x[((size_t)(b * CC + lane + 64) * LL) + p];
    float v2 = x[((size_t)(b * CC + lane + 128) * LL) + p];
    float s = v0 + v1 + v2, sq = v0 * v0 + v1 * v1 + v2 * v2;
    #pragma unroll
    for (int o = 1; o < 64; o <<= 1) { s += __shfl_xor(s, o); sq += __shfl_xor(sq, o); }
    float mu = s * (1.f / 192.f);
    float var = sq * (1.f / 192.f) - mu * mu;
    float rs = rsqrtf(var + 1e-6f);
    const float* mb = mods + b * 1152;
    size_t base = ((size_t)(b * LL + p)) * CC;
    int c0 = lane, c1 = lane + 64, c2 = lane + 128;
    hmod[base + c0] = (v0 - mu) * rs * (1.f + mb[192 + c0]) + mb[c0];
    hmod[base + c1] = (v1 - mu) * rs * (1.f + mb[192 + c1]) + mb[c1];
    hmod[base + c2] = (v2 - mu) * rs * (1.f + mb[192 + c2]) + mb[c2];
}

// K3: xz = hmod @ W_in + b_in, 8 tokens/block, 256 threads
__global__ void k_xz(const float* __restrict__ hmod, const float* __restrict__ W_in,
                     const float* __restrict__ b_in, float* __restrict__ xz) {
    __shared__ float hs[8][CC];
    int tok0 = blockIdx.x * 8;       // 2048 blocks
    int t = threadIdx.x;             // 256
    for (int i = t; i < 8 * CC; i += 256) hs[i / CC][i % CC] = hmod[(size_t)tok0 * CC + i];
    __syncthreads();
    float b0 = b_in[t], b1 = b_in[t + 256], b2 = b_in[t + 512];
    float acc[8][3];
    #pragma unroll
    for (int i = 0; i < 8; ++i) { acc[i][0] = b0; acc[i][1] = b1; acc[i][2] = b2; }
    for (int k = 0; k < CC; ++k) {
        const float* wr = W_in + k * 768;
        float w0 = wr[t], w1 = wr[t + 256], w2 = wr[t + 512];
        #pragma unroll
        for (int i = 0; i < 8; ++i) {
            float hv = hs[i][k];
            acc[i][0] = fmaf(hv, w0, acc[i][0]);
            acc[i][1] = fmaf(hv, w1, acc[i][1]);
            acc[i][2] = fmaf(hv, w2, acc[i][2]);
        }
    }
    #pragma unroll
    for (int i = 0; i < 8; ++i) {
        float* orow = xz + ((size_t)tok0 + i) * 768;
        orow[t] = acc[i][0]; orow[t + 256] = acc[i][1]; orow[t + 512] = acc[i][2];
    }
}

// K4: per (seq,l): conv+silu -> xv; dbl44 -> dbl48 store; dtv=softplus(...);
// pack (dtv,dtx) bf16x2 dword into dtvx[seq][g96][l][ch&3]; zs4 likewise (all dirs).
__global__ void k_conv_dbl(const float* __restrict__ xz, const float* __restrict__ conv_w,
                           const float* __restrict__ conv_b, const float* __restrict__ W_x,
                           const float* __restrict__ W_dt, const float* __restrict__ b_dt,
                           float* __restrict__ dbl48,
                           uint32* __restrict__ dtvx, ushort16* __restrict__ zs4) {
    __shared__ float xcs[DI];
    __shared__ float red[352];
    __shared__ float dbls[DTR];
    int blk = blockIdx.x;            // 65536 = seq*4096 + l
    int seq = blk >> 12;
    int l = blk & 4095;
    int dir = seq >> 2, b = seq & 3;
    int t = threadIdx.x;             // 384
    int p_here = perm_pos(dir, l);
    float xv;
    {
        float acc = conv_b[t];
        #pragma unroll
        for (int k = 0; k < 4; ++k) {
            int lk = l - 3 + k;
            if (lk >= 0) {
                int p = perm_pos(dir, lk);
                acc = fmaf(xz[((size_t)(b * LL + p)) * 768 + t], conv_w[t * 4 + k], acc);
            }
        }
        xv = siluf(acc);
        xcs[t] = xv;
    }
    __syncthreads();
    if (t < 352) {
        int j = t >> 3, i = t & 7;
        float ps = 0.f;
        int k0 = i * 48;
        #pragma unroll 8
        for (int kk = 0; kk < 48; ++kk)
            ps = fmaf(xcs[k0 + kk], W_x[(k0 + kk) * 44 + j], ps);
        red[t] = ps;
    }
    __syncthreads();
    if (t < 44) {
        float sum = 0.f;
        #pragma unroll
        for (int i = 0; i < 8; ++i) sum += red[t * 8 + i];
        if (t < DTR) dbls[t] = sum;
        dbl48[((size_t)blk) * 48 + t] = sum;   // [0:12)=dt-rank, [12:28)=B, [28:44)=C
    }
    __syncthreads();
    {
        float acc = b_dt[t];
        #pragma unroll
        for (int r = 0; r < DTR; ++r) acc = fmaf(dbls[r], W_dt[r * DI + t], acc);
        float sp = (acc > 15.f) ? acc : __logf(1.f + __expf(acc));
        sp = fmaxf(sp, 1e-12f);
        __hip_bfloat16 hv = __float2bfloat16(sp);
        __hip_bfloat16 hx = __float2bfloat16(sp * xv);
        uint32 pack = ((uint32)(*(ushort16*)&hx) << 16) | (uint32)(*(ushort16*)&hv);
        size_t R = ((size_t)(seq * 96 + (t >> 2)) * LL + l);
        dtvx[R * 4 + (t & 3)] = pack;
        float zvv = xz[((size_t)(b * LL + p_here)) * 768 + DI + t];
        __hip_bfloat16 hz = __float2bfloat16(0.25f * siluf(zvv));
        zs4[R * 4 + (t & 3)] = *(ushort16*)&hz;
    }
}

// K5a: per-chunk local scan -> final state FH, decay product P
__global__ void k_scanA(const uint32* __restrict__ dtvx, const float* __restrict__ dbl48,
                        const float* __restrict__ A_log,
                        float* __restrict__ FH, float* __restrict__ Parr) {
    int blk = blockIdx.x;            // (seq*NC + c)*24 + gblk ; 12288 blocks
    int gblk = blk % 24;
    int sc = blk / 24;
    int c = sc & (NC - 1);
    int seq = sc / NC;
    int w = threadIdx.x >> 6, lane = threadIdx.x & 63;
    int g96 = gblk * 4 + w;
    int s = lane & 15, g = lane >> 4;
    int d = g96 * 4 + g;
    float a_s = -__expf(A_log[d * DST + s]);
    int l0 = c * CL;
    const uint32* pdt = dtvx + ((size_t)(seq * 96 + g96) * LL + l0) * 4 + g;
    const float* dbc = dbl48 + ((size_t)(seq * LL) + l0) * 48;
    float h = 0.f, P = 1.f;
    #pragma unroll 4
    for (int l = 0; l < CL; ++l) {
        uint32 u = pdt[l * 4];
        float dtv = bf16lo(u);
        float dtx = bf16hi(u);
        float Bv = dbc[l * 48 + 12 + s];
        float dA = __expf(dtv * a_s);
        h = fmaf(h, dA, dtx * Bv);
        P *= dA;
    }
    size_t o = ((size_t)(seq * NC + c) * 96 + g96) * 64 + lane;
    FH[o] = h;
    Parr[o] = P;
}

// K5b: chunk-state prefix: Hin_c = H; H = F_c + P_c*H  (FH overwritten with Hin)
__global__ void k_scanB(float* __restrict__ FH, const float* __restrict__ Parr) {
    int wid = blockIdx.x * 4 + (threadIdx.x >> 6);   // 384 blocks -> 1536 waves
    int lane = threadIdx.x & 63;
    int seq = wid / 96, g96 = wid % 96;
    float H = 0.f;
    for (int c = 0; c < NC; ++c) {
        size_t o = ((size_t)(seq * NC + c) * 96 + g96) * 64 + lane;
        float F = FH[o], P = Parr[o];
        FH[o] = H;
        H = fmaf(P, H, F);
    }
}

// K5c: local scan seeded with Hin, emit y; atomicAdd zs*(pr + D*xv) into ysum[(b,p,d)]
__global__ void k_scanC(const uint32* __restrict__ dtvx, const float* __restrict__ dbl48,
                        const ushort16* __restrict__ zs4, const float* __restrict__ FH,
                        const float* __restrict__ A_log, const float* __restrict__ Dp,
                        float* __restrict__ ysum) {
    int blk = blockIdx.x;
    int gblk = blk % 24;
    int sc = blk / 24;
    int c = sc & (NC - 1);
    int seq = sc / NC;
    int w = threadIdx.x >> 6, lane = threadIdx.x & 63;
    int g96 = gblk * 4 + w;
    int s = lane & 15, g = lane >> 4;
    int d = g96 * 4 + g;
    int dir = seq >> 2, b = seq & 3;
    float a_s = -__expf(A_log[d * DST + s]);
    float D_d = Dp[d];
    int l0 = c * CL;
    const uint32* pdt = dtvx + ((size_t)(seq * 96 + g96) * LL + l0) * 4 + g;
    const ushort16* pzs = zs4 + ((size_t)(seq * 96 + g96) * LL + l0) * 4 + g;
    const float* dbc = dbl48 + ((size_t)(seq * LL) + l0) * 48;
    float* yb = ysum + (size_t)(b * LL) * DI + d;
    float h = FH[((size_t)(seq * NC + c) * 96 + g96) * 64 + lane];
    #pragma unroll 4
    for (int l = 0; l < CL; ++l) {
        uint32 u = pdt[l * 4];
        float dtv = bf16lo(u);
        float dtx = bf16hi(u);
        float Bv = dbc[l * 48 + 12 + s];
        float Cv = dbc[l * 48 + 28 + s];
        float dA = __expf(dtv * a_s);
        h = fmaf(h, dA, dtx * Bv);
        float pr = h * Cv;
        pr += __shfl_xor(pr, 1);
        pr += __shfl_xor(pr, 2);
        pr += __shfl_xor(pr, 4);
        pr += __shfl_xor(pr, 8);
        if (s == 0) {
            float xv = dtv > 0.f ? dtx * __builtin_amdgcn_rcpf(dtv) : 0.f;
            float y = pr + D_d * xv;
            int p = perm_pos(dir, l0 + l);
            ushort16 uz = pzs[l * 4];
            float zsv = __uint_as_float((uint32)uz << 16);
            atomicAdd(&yb[(size_t)p * DI], zsv * y);
        }
    }
}

// K6: ysum @ W_out + b_out, residual with g1 -> tok2 ; 8 tokens/block, 192 threads
__global__ void k_out_gemm(const float* __restrict__ ysum, const float* __restrict__ W_out,
                           const float* __restrict__ b_out, const float* __restrict__ x,
                           const float* __restrict__ mods, float* __restrict__ tok2) {
    __shared__ float ys[8][DI];
    int tok0 = blockIdx.x * 8;       // 2048 blocks
    int b = tok0 >> 12;
    int p0 = tok0 & 4095;
    int t = threadIdx.x;             // 192
    for (int i = t; i < 8 * DI; i += 192) ys[i / DI][i % DI] = ysum[(size_t)tok0 * DI + i];
    __syncthreads();
    float acc[8];
    #pragma unroll
    for (int i = 0; i < 8; ++i) acc[i] = 0.f;
    for (int k = 0; k < DI; ++k) {
        float wv = W_out[k * CC + t];
        #pragma unroll
        for (int i = 0; i < 8; ++i) acc[i] = fmaf(ys[i][k], wv, acc[i]);
    }
    float bo = b_out[t];
    float g1 = mods[b * 1152 + 384 + t];
    const float* xr = x + ((size_t)(b * CC + t)) * LL + p0;
    #pragma unroll
    for (int i = 0; i < 8; ++i) {
        tok2[((size_t)tok0 + i) * CC + t] = xr[i] + g1 * (acc[i] + bo);
    }
}

// K7: m = modulate(LN(tok2), sh2, sc2); a1 = gelu(m @ w1 + b1); 8 tokens/block, 256 thr
__global__ void k_mlp1(const float* __restrict__ tok2, const float* __restrict__ mods,
                       const float* __restrict__ w1, const float* __restrict__ b1,
                       float* __restrict__ a1) {
    __shared__ float ms[8][CC];
    int tok0 = blockIdx.x * 8;       // 2048 blocks
    int b = tok0 >> 12;
    int t = threadIdx.x;             // 256
    for (int i = t; i < 8 * CC; i += 256) ms[i / CC][i % CC] = tok2[(size_t)tok0 * CC + i];
    __syncthreads();
    // LN+modulate: 8 groups of 32 threads
    {
        int i = t >> 5, ln = t & 31;
        float s = 0.f, sq = 0.f;
        for (int j = ln; j < CC; j += 32) { float v = ms[i][j]; s += v; sq += v * v; }
        #pragma unroll
        for (int o = 1; o < 32; o <<= 1) { s += __shfl_xor(s, o); sq += __shfl_xor(sq, o); }
        float mu = s * (1.f / 192.f);
        float var = sq * (1.f / 192.f) - mu * mu;
        float rs = rsqrtf(var + 1e-6f);
        const float* mb = mods + b * 1152;
        for (int j = ln; j < CC; j += 32) {
            ms[i][j] = (ms[i][j] - mu) * rs * (1.f + mb[768 + j]) + mb[576 + j];
        }
    }
    __syncthreads();
    float bb0 = b1[t], bb1 = b1[t + 256], bb2 = b1[t + 512];
    float acc[8][3];
    #pragma unroll
    for (int i = 0; i < 8; ++i) { acc[i][0] = bb0; acc[i][1] = bb1; acc[i][2] = bb2; }
    for (int k = 0; k < CC; ++k) {
        const float* wr = w1 + k * 768;
        float w0 = wr[t], wv1 = wr[t + 256], wv2 = wr[t + 512];
        #pragma unroll
        for (int i = 0; i < 8; ++i) {
            float mv = ms[i][k];
            acc[i][0] = fmaf(mv, w0, acc[i][0]);
            acc[i][1] = fmaf(mv, wv1, acc[i][1]);
            acc[i][2] = fmaf(mv, wv2, acc[i][2]);
        }
    }
    #pragma unroll
    for (int i = 0; i < 8; ++i) {
        float* orow = a1 + ((size_t)tok0 + i) * 768;
        #pragma unroll
        for (int r = 0; r < 3; ++r) {
            float u = acc[i][r];
            float inner = 0.7978845608028654f * (u + 0.044715f * u * u * u);
            float e = __expf(2.f * inner);
            float th = 1.f - 2.f / (e + 1.f);
            orow[t + 256 * r] = 0.5f * u * (1.f + th);
        }
    }
}

// K8: out = tok2 + g2 * (a1 @ w2 + b2), (b,C,h,w) layout; 8 tokens/block, 192 thr
__global__ void k_mlp2(const float* __restrict__ a1, const float* __restrict__ tok2,
                       const float* __restrict__ mods, const float* __restrict__ w2,
                       const float* __restrict__ b2, float* __restrict__ out) {
    __shared__ float as[8][768];
    int tok0 = blockIdx.x * 8;       // 2048 blocks
    int b = tok0 >> 12;
    int p0 = tok0 & 4095;
    int t = threadIdx.x;             // 192
    for (int i = t; i < 8 * 768; i += 192) as[i / 768][i % 768] = a1[(size_t)tok0 * 768 + i];
    __syncthreads();
    float acc[8];
    float bb = b2[t];
    #pragma unroll
    for (int i = 0; i < 8; ++i) acc[i] = bb;
    for (int k = 0; k < 768; ++k) {
        float wv = w2[k * CC + t];
        #pragma unroll
        for (int i = 0; i < 8; ++i) acc[i] = fmaf(as[i][k], wv, acc[i]);
    }
    float g2 = mods[b * 1152 + 960 + t];
    float* orow = out + ((size_t)(b * CC + t)) * LL + p0;
    #pragma unroll
    for (int i = 0; i < 8; ++i) {
        orow[i] = tok2[((size_t)tok0 + i) * CC + t] + g2 * acc[i];
    }
}

extern "C" void kernel_launch(void* const* d_in, const int* in_sizes, int n_in,
                              void* d_out, int out_size, void* d_ws, size_t ws_size,
                              hipStream_t stream) {
    const float* x       = (const float*)d_in[0];
    const float* c       = (const float*)d_in[1];
    const float* adaln_w = (const float*)d_in[2];
    const float* adaln_b = (const float*)d_in[3];
    const float* W_in    = (const float*)d_in[4];
    const float* b_in    = (const float*)d_in[5];
    const float* conv_w  = (const float*)d_in[6];
    const float* conv_b  = (const float*)d_in[7];
    const float* W_x     = (const float*)d_in[8];
    const float* W_dt    = (const float*)d_in[9];
    const float* b_dt    = (const float*)d_in[10];
    const float* A_log   = (const float*)d_in[11];
    const float* Dp      = (const float*)d_in[12];
    const float* W_out   = (const float*)d_in[13];
    const float* b_out   = (const float*)d_in[14];
    const float* w1      = (const float*)d_in[15];
    const float* b1      = (const float*)d_in[16];
    const float* w2      = (const float*)d_in[17];
    const float* b2      = (const float*)d_in[18];

    // workspace (~239 MB), time-aliased:
    //  regB (12.6MB): hmod (k2-k3) -> dbl48 (k4, scans) -> tok2 (k6-k8)
    //  regC (50MB):   xz (k3-k4) -> ysum (25MB, scanC-k6) -> a1 (k7-k8)
    float* ws = (float*)d_ws;
    float* mods  = ws;                                  // 4,608
    float* regB  = ws + 4608;                           // 3,145,728 f32
    float* regC  = regB + 3145728;                      // 12,582,912 f32
    uint32* dtvx = (uint32*)(regC + 12582912);          // 25,165,824 u32 (bf16x2)
    ushort16* zs4 = (ushort16*)(dtvx + 25165824);       // 25,165,824 u16
    float* FH    = (float*)(zs4 + 25165824);            // 3,145,728 f32
    float* Parr  = FH + 3145728;                        // 3,145,728 f32
    float* out   = (float*)d_out;

    float* hmod  = regB;
    float* dbl48 = regB;
    float* tok2  = regB;
    float* xz    = regC;
    float* ysum  = regC;
    float* a1    = regC;

    k_mods<<<18, 256, 0, stream>>>(c, adaln_w, adaln_b, mods);
    k_ln_mod<<<4096, 256, 0, stream>>>(x, mods, hmod);
    k_xz<<<2048, 256, 0, stream>>>(hmod, W_in, b_in, xz);
    k_conv_dbl<<<65536, 384, 0, stream>>>(xz, conv_w, conv_b, W_x, W_dt, b_dt,
                                          dbl48, dtvx, zs4);
    hipMemsetAsync(ysum, 0, (size_t)6291456 * sizeof(float), stream);
    k_scanA<<<12288, 256, 0, stream>>>(dtvx, dbl48, A_log, FH, Parr);
    k_scanB<<<384, 256, 0, stream>>>(FH, Parr);
    k_scanC<<<12288, 256, 0, stream>>>(dtvx, dbl48, zs4, FH, A_log, Dp, ysum);
    k_out_gemm<<<2048, 192, 0, stream>>>(ysum, W_out, b_out, x, mods, tok2);
    k_mlp1<<<2048, 256, 0, stream>>>(tok2, mods, w1, b1, a1);
    k_mlp2<<<2048, 192, 0, stream>>>(a1, tok2, mods, w2, b2, out);
}

// Round 6
// 1403.375 us; speedup vs baseline: 5.0069x; 1.7773x over previous
//
#include <hip/hip_runtime.h>
#include <hip/hip_bf16.h>

// Problem constants
#define NB   4       // batch
#define CC   192     // d_model
#define LL   4096    // H*W
#define DI   384     // d_inner
#define DST  16      // d_state
#define DTR  12      // dt_rank
#define NC   32      // scan chunks
#define CL   128     // chunk length

typedef unsigned int uint32;
typedef unsigned short ushort16;

__device__ __forceinline__ float siluf(float x) {
    return x / (1.f + __expf(-x));
}
__device__ __forceinline__ float bf16lo(uint32 u) { return __uint_as_float(u << 16); }
__device__ __forceinline__ float bf16hi(uint32 u) { return __uint_as_float(u & 0xffff0000u); }

// scan-position l -> token position p, per direction
__device__ __forceinline__ int perm_pos(int dir, int l) {
    if (dir == 0) return l;
    if (dir == 1) return 4095 - l;
    if (dir == 2) return ((l & 63) << 6) | (l >> 6);
    int m = 4095 - l;
    return ((m & 63) << 6) | (m >> 6);
}

// K1: mods = silu(c) @ adaln_w + adaln_b   (4 x 1152)
__global__ void k_mods(const float* __restrict__ c, const float* __restrict__ w,
                       const float* __restrict__ bias, float* __restrict__ mods) {
    int idx = blockIdx.x * 256 + threadIdx.x;
    if (idx >= NB * 1152) return;
    int n = idx / 1152, j = idx % 1152;
    float acc = bias[j];
    for (int k = 0; k < CC; ++k) {
        acc = fmaf(siluf(c[n * CC + k]), w[k * 1152 + j], acc);
    }
    mods[idx] = acc;
}

// K2: hmod = modulate(LN(tokens), sh1, sc1)
__global__ void k_ln_mod(const float* __restrict__ x, const float* __restrict__ mods,
                         float* __restrict__ hmod) {
    int wave = blockIdx.x * 4 + (threadIdx.x >> 6);
    int lane = threadIdx.x & 63;
    int b = wave >> 12;
    int p = wave & 4095;
    float v0 = x[((size_t)(b * CC + lane) * LL) + p];
    float v1 = x[((size_t)(b * CC + lane + 64) * LL) + p];
    float v2 = x[((size_t)(b * CC + lane + 128) * LL) + p];
    float s = v0 + v1 + v2, sq = v0 * v0 + v1 * v1 + v2 * v2;
    #pragma unroll
    for (int o = 1; o < 64; o <<= 1) { s += __shfl_xor(s, o); sq += __shfl_xor(sq, o); }
    float mu = s * (1.f / 192.f);
    float var = sq * (1.f / 192.f) - mu * mu;
    float rs = rsqrtf(var + 1e-6f);
    const float* mb = mods + b * 1152;
    size_t base = ((size_t)(b * LL + p)) * CC;
    int c0 = lane, c1 = lane + 64, c2 = lane + 128;
    hmod[base + c0] = (v0 - mu) * rs * (1.f + mb[192 + c0]) + mb[c0];
    hmod[base + c1] = (v1 - mu) * rs * (1.f + mb[192 + c1]) + mb[c1];
    hmod[base + c2] = (v2 - mu) * rs * (1.f + mb[192 + c2]) + mb[c2];
}

// K3: xz = hmod @ W_in + b_in, 8 tokens/block, 256 threads
__global__ void k_xz(const float* __restrict__ hmod, const float* __restrict__ W_in,
                     const float* __restrict__ b_in, float* __restrict__ xz) {
    __shared__ float hs[8][CC];
    int tok0 = blockIdx.x * 8;       // 2048 blocks
    int t = threadIdx.x;             // 256
    for (int i = t; i < 8 * CC; i += 256) hs[i / CC][i % CC] = hmod[(size_t)tok0 * CC + i];
    __syncthreads();
    float b0 = b_in[t], b1 = b_in[t + 256], b2 = b_in[t + 512];
    float acc[8][3];
    #pragma unroll
    for (int i = 0; i < 8; ++i) { acc[i][0] = b0; acc[i][1] = b1; acc[i][2] = b2; }
    for (int k = 0; k < CC; ++k) {
        const float* wr = W_in + k * 768;
        float w0 = wr[t], w1 = wr[t + 256], w2 = wr[t + 512];
        #pragma unroll
        for (int i = 0; i < 8; ++i) {
            float hv = hs[i][k];
            acc[i][0] = fmaf(hv, w0, acc[i][0]);
            acc[i][1] = fmaf(hv, w1, acc[i][1]);
            acc[i][2] = fmaf(hv, w2, acc[i][2]);
        }
    }
    #pragma unroll
    for (int i = 0; i < 8; ++i) {
        float* orow = xz + ((size_t)tok0 + i) * 768;
        orow[t] = acc[i][0]; orow[t + 256] = acc[i][1]; orow[t + 512] = acc[i][2];
    }
}

// K4: 8 tokens/block, 384 threads. conv+silu -> xcs (LDS); dbl44 = xc@W_x -> dbl48;
// dt = softplus(dbl[:12]@W_dt + b_dt); pack (dtv, dtv*xv) bf16x2 -> dtvx[seq][l][384].
__global__ void k_conv_dbl(const float* __restrict__ xz, const float* __restrict__ conv_w,
                           const float* __restrict__ conv_b, const float* __restrict__ W_x,
                           const float* __restrict__ W_dt, const float* __restrict__ b_dt,
                           float* __restrict__ dbl48, uint32* __restrict__ dtvx) {
    __shared__ float xcs[8][DI];
    __shared__ float dbls[8][DTR];
    int blk = blockIdx.x;            // 8192 = seq*512 + lb
    int seq = blk >> 9;
    int lb = blk & 511;
    int l0 = lb * 8;
    int dir = seq >> 2, b = seq & 3;
    int t = threadIdx.x;             // 384
    // phase 1: conv + silu for 8 tokens, channel t, via 11-sample window
    {
        float cw0 = conv_w[t * 4 + 0], cw1 = conv_w[t * 4 + 1];
        float cw2 = conv_w[t * 4 + 2], cw3 = conv_w[t * 4 + 3];
        float cb = conv_b[t];
        float xwin[11];
        #pragma unroll
        for (int i = 0; i < 11; ++i) {
            int lk = l0 - 3 + i;
            xwin[i] = (lk >= 0)
                ? xz[((size_t)(b * LL + perm_pos(dir, lk))) * 768 + t] : 0.f;
        }
        #pragma unroll
        for (int i = 0; i < 8; ++i) {
            float acc = cb;
            acc = fmaf(cw0, xwin[i], acc);
            acc = fmaf(cw1, xwin[i + 1], acc);
            acc = fmaf(cw2, xwin[i + 2], acc);
            acc = fmaf(cw3, xwin[i + 3], acc);
            xcs[i][t] = siluf(acc);
        }
    }
    __syncthreads();
    // phase 2: dbl44 per token; 352 threads = 8 tokens x 44 outputs, K=384
    if (t < 352) {
        int i = t / 44, j = t - i * 44;
        float ps = 0.f;
        #pragma unroll 4
        for (int k = 0; k < DI; ++k) ps = fmaf(xcs[i][k], W_x[k * 44 + j], ps);
        if (j < DTR) dbls[i][j] = ps;
        dbl48[((size_t)(seq * LL) + l0 + i) * 48 + j] = ps;
    }
    __syncthreads();
    // phase 3: dt for 8 tokens, channel t
    {
        float wdtc[DTR];
        #pragma unroll
        for (int r = 0; r < DTR; ++r) wdtc[r] = W_dt[r * DI + t];
        float bdt = b_dt[t];
        #pragma unroll
        for (int i = 0; i < 8; ++i) {
            float acc = bdt;
            #pragma unroll
            for (int r = 0; r < DTR; ++r) acc = fmaf(dbls[i][r], wdtc[r], acc);
            float sp = (acc > 15.f) ? acc : __logf(1.f + __expf(acc));
            sp = fmaxf(sp, 1e-12f);
            float xv = xcs[i][t];
            __hip_bfloat16 hv = __float2bfloat16(sp);
            __hip_bfloat16 hx = __float2bfloat16(sp * xv);
            uint32 pack = ((uint32)(*(ushort16*)&hx) << 16) | (uint32)(*(ushort16*)&hv);
            dtvx[((size_t)(seq * LL) + l0 + i) * DI + t] = pack;
        }
    }
}

// K5a: per-chunk local scan -> final state FH, decay product P
__global__ void k_scanA(const uint32* __restrict__ dtvx, const float* __restrict__ dbl48,
                        const float* __restrict__ A_log,
                        float* __restrict__ FH, float* __restrict__ Parr) {
    int blk = blockIdx.x;            // (seq*NC + c)*24 + gblk ; 12288 blocks
    int gblk = blk % 24;
    int sc = blk / 24;
    int c = sc & (NC - 1);
    int seq = sc / NC;
    int w = threadIdx.x >> 6, lane = threadIdx.x & 63;
    int g96 = gblk * 4 + w;
    int s = lane & 15, g = lane >> 4;
    int d = g96 * 4 + g;
    float a_s = -__expf(A_log[d * DST + s]);
    int l0 = c * CL;
    const uint32* pdt = dtvx + ((size_t)(seq * LL) + l0) * DI + d;
    const float* dbc = dbl48 + ((size_t)(seq * LL) + l0) * 48;
    float h = 0.f, P = 1.f;
    #pragma unroll 4
    for (int l = 0; l < CL; ++l) {
        uint32 u = pdt[(size_t)l * DI];
        float dtv = bf16lo(u);
        float dtx = bf16hi(u);
        float Bv = dbc[l * 48 + 12 + s];
        float dA = __expf(dtv * a_s);
        h = fmaf(h, dA, dtx * Bv);
        P *= dA;
    }
    size_t o = ((size_t)(seq * NC + c) * 96 + g96) * 64 + lane;
    FH[o] = h;
    Parr[o] = P;
}

// K5b: chunk-state prefix: Hin_c = H; H = F_c + P_c*H  (FH overwritten with Hin)
__global__ void k_scanB(float* __restrict__ FH, const float* __restrict__ Parr) {
    int wid = blockIdx.x * 4 + (threadIdx.x >> 6);   // 384 blocks -> 1536 waves
    int lane = threadIdx.x & 63;
    int seq = wid / 96, g96 = wid % 96;
    float H = 0.f;
    for (int c = 0; c < NC; ++c) {
        size_t o = ((size_t)(seq * NC + c) * 96 + g96) * 64 + lane;
        float F = FH[o], P = Parr[o];
        FH[o] = H;
        H = fmaf(P, H, F);
    }
}

// K5c: local scan seeded with Hin, emit raw y; atomicAdd into ysum[(b,p,d)]
__global__ void k_scanC(const uint32* __restrict__ dtvx, const float* __restrict__ dbl48,
                        const float* __restrict__ FH,
                        const float* __restrict__ A_log, const float* __restrict__ Dp,
                        float* __restrict__ ysum) {
    int blk = blockIdx.x;
    int gblk = blk % 24;
    int sc = blk / 24;
    int c = sc & (NC - 1);
    int seq = sc / NC;
    int w = threadIdx.x >> 6, lane = threadIdx.x & 63;
    int g96 = gblk * 4 + w;
    int s = lane & 15, g = lane >> 4;
    int d = g96 * 4 + g;
    int dir = seq >> 2, b = seq & 3;
    float a_s = -__expf(A_log[d * DST + s]);
    float D_d = Dp[d];
    int l0 = c * CL;
    const uint32* pdt = dtvx + ((size_t)(seq * LL) + l0) * DI + d;
    const float* dbc = dbl48 + ((size_t)(seq * LL) + l0) * 48;
    float* yb = ysum + (size_t)(b * LL) * DI + d;
    float h = FH[((size_t)(seq * NC + c) * 96 + g96) * 64 + lane];
    #pragma unroll 4
    for (int l = 0; l < CL; ++l) {
        uint32 u = pdt[(size_t)l * DI];
        float dtv = bf16lo(u);
        float dtx = bf16hi(u);
        float Bv = dbc[l * 48 + 12 + s];
        float Cv = dbc[l * 48 + 28 + s];
        float dA = __expf(dtv * a_s);
        h = fmaf(h, dA, dtx * Bv);
        float pr = h * Cv;
        pr += __shfl_xor(pr, 1);
        pr += __shfl_xor(pr, 2);
        pr += __shfl_xor(pr, 4);
        pr += __shfl_xor(pr, 8);
        if (s == 0) {
            float xv = dtv > 0.f ? dtx * __builtin_amdgcn_rcpf(dtv) : 0.f;
            float y = pr + D_d * xv;
            int p = perm_pos(dir, l0 + l);
            atomicAdd(&yb[(size_t)p * DI], y);
        }
    }
}

// K6: ys = ysum * 0.25*silu(z); tok2 = x + g1*(ys@W_out + b_out); 8 tok/block, 192 thr
__global__ void k_out_gemm(const float* __restrict__ ysum, const float* __restrict__ xz,
                           const float* __restrict__ W_out, const float* __restrict__ b_out,
                           const float* __restrict__ x, const float* __restrict__ mods,
                           float* __restrict__ tok2) {
    __shared__ float ys[8][DI];
    int tok0 = blockIdx.x * 8;       // 2048 blocks
    int b = tok0 >> 12;
    int p0 = tok0 & 4095;
    int t = threadIdx.x;             // 192
    for (int i = t; i < 8 * DI; i += 192) {
        int tok = i / DI, k = i % DI;
        float zv = xz[((size_t)tok0 + tok) * 768 + DI + k];
        ys[tok][k] = ysum[(size_t)tok0 * DI + i] * 0.25f * siluf(zv);
    }
    __syncthreads();
    float acc[8];
    #pragma unroll
    for (int i = 0; i < 8; ++i) acc[i] = 0.f;
    for (int k = 0; k < DI; ++k) {
        float wv = W_out[k * CC + t];
        #pragma unroll
        for (int i = 0; i < 8; ++i) acc[i] = fmaf(ys[i][k], wv, acc[i]);
    }
    float bo = b_out[t];
    float g1 = mods[b * 1152 + 384 + t];
    const float* xr = x + ((size_t)(b * CC + t)) * LL + p0;
    #pragma unroll
    for (int i = 0; i < 8; ++i) {
        tok2[((size_t)tok0 + i) * CC + t] = xr[i] + g1 * (acc[i] + bo);
    }
}

// K7: m = modulate(LN(tok2), sh2, sc2); a1 = gelu(m @ w1 + b1); 8 tokens/block, 256 thr
__global__ void k_mlp1(const float* __restrict__ tok2, const float* __restrict__ mods,
                       const float* __restrict__ w1, const float* __restrict__ b1,
                       float* __restrict__ a1) {
    __shared__ float ms[8][CC];
    int tok0 = blockIdx.x * 8;       // 2048 blocks
    int b = tok0 >> 12;
    int t = threadIdx.x;             // 256
    for (int i = t; i < 8 * CC; i += 256) ms[i / CC][i % CC] = tok2[(size_t)tok0 * CC + i];
    __syncthreads();
    {
        int i = t >> 5, ln = t & 31;
        float s = 0.f, sq = 0.f;
        for (int j = ln; j < CC; j += 32) { float v = ms[i][j]; s += v; sq += v * v; }
        #pragma unroll
        for (int o = 1; o < 32; o <<= 1) { s += __shfl_xor(s, o); sq += __shfl_xor(sq, o); }
        float mu = s * (1.f / 192.f);
        float var = sq * (1.f / 192.f) - mu * mu;
        float rs = rsqrtf(var + 1e-6f);
        const float* mb = mods + b * 1152;
        for (int j = ln; j < CC; j += 32) {
            ms[i][j] = (ms[i][j] - mu) * rs * (1.f + mb[768 + j]) + mb[576 + j];
        }
    }
    __syncthreads();
    float bb0 = b1[t], bb1 = b1[t + 256], bb2 = b1[t + 512];
    float acc[8][3];
    #pragma unroll
    for (int i = 0; i < 8; ++i) { acc[i][0] = bb0; acc[i][1] = bb1; acc[i][2] = bb2; }
    for (int k = 0; k < CC; ++k) {
        const float* wr = w1 + k * 768;
        float w0 = wr[t], wv1 = wr[t + 256], wv2 = wr[t + 512];
        #pragma unroll
        for (int i = 0; i < 8; ++i) {
            float mv = ms[i][k];
            acc[i][0] = fmaf(mv, w0, acc[i][0]);
            acc[i][1] = fmaf(mv, wv1, acc[i][1]);
            acc[i][2] = fmaf(mv, wv2, acc[i][2]);
        }
    }
    #pragma unroll
    for (int i = 0; i < 8; ++i) {
        float* orow = a1 + ((size_t)tok0 + i) * 768;
        #pragma unroll
        for (int r = 0; r < 3; ++r) {
            float u = acc[i][r];
            float inner = 0.7978845608028654f * (u + 0.044715f * u * u * u);
            float e = __expf(2.f * inner);
            float th = 1.f - 2.f / (e + 1.f);
            orow[t + 256 * r] = 0.5f * u * (1.f + th);
        }
    }
}

// K8: out = tok2 + g2 * (a1 @ w2 + b2), (b,C,h,w) layout; 8 tokens/block, 192 thr
__global__ void k_mlp2(const float* __restrict__ a1, const float* __restrict__ tok2,
                       const float* __restrict__ mods, const float* __restrict__ w2,
                       const float* __restrict__ b2, float* __restrict__ out) {
    __shared__ float as[8][768];
    int tok0 = blockIdx.x * 8;       // 2048 blocks
    int b = tok0 >> 12;
    int p0 = tok0 & 4095;
    int t = threadIdx.x;             // 192
    for (int i = t; i < 8 * 768; i += 192) as[i / 768][i % 768] = a1[(size_t)tok0 * 768 + i];
    __syncthreads();
    float acc[8];
    float bb = b2[t];
    #pragma unroll
    for (int i = 0; i < 8; ++i) acc[i] = bb;
    for (int k = 0; k < 768; ++k) {
        float wv = w2[k * CC + t];
        #pragma unroll
        for (int i = 0; i < 8; ++i) acc[i] = fmaf(as[i][k], wv, acc[i]);
    }
    float g2 = mods[b * 1152 + 960 + t];
    float* orow = out + ((size_t)(b * CC + t)) * LL + p0;
    #pragma unroll
    for (int i = 0; i < 8; ++i) {
        orow[i] = tok2[((size_t)tok0 + i) * CC + t] + g2 * acc[i];
    }
}

extern "C" void kernel_launch(void* const* d_in, const int* in_sizes, int n_in,
                              void* d_out, int out_size, void* d_ws, size_t ws_size,
                              hipStream_t stream) {
    const float* x       = (const float*)d_in[0];
    const float* c       = (const float*)d_in[1];
    const float* adaln_w = (const float*)d_in[2];
    const float* adaln_b = (const float*)d_in[3];
    const float* W_in    = (const float*)d_in[4];
    const float* b_in    = (const float*)d_in[5];
    const float* conv_w  = (const float*)d_in[6];
    const float* conv_b  = (const float*)d_in[7];
    const float* W_x     = (const float*)d_in[8];
    const float* W_dt    = (const float*)d_in[9];
    const float* b_dt    = (const float*)d_in[10];
    const float* A_log   = (const float*)d_in[11];
    const float* Dp      = (const float*)d_in[12];
    const float* W_out   = (const float*)d_in[13];
    const float* b_out   = (const float*)d_in[14];
    const float* w1      = (const float*)d_in[15];
    const float* b1      = (const float*)d_in[16];
    const float* w2      = (const float*)d_in[17];
    const float* b2      = (const float*)d_in[18];

    // workspace (~214 MB):
    //  regB (12.6MB): hmod (k2-k3) -> dbl48 (k4-scans) -> tok2 (k6-k8)
    //  xzbuf (50MB):  xz (k3-k6) -> a1 (k7-k8)
    //  ysum (25MB), dtvx (100MB), FH/Parr (12.6MB each)
    float* ws = (float*)d_ws;
    float* mods  = ws;                                  // 4,608
    float* regB  = ws + 4608;                           // 3,145,728 f32
    float* xzbuf = regB + 3145728;                      // 12,582,912 f32
    float* ysum  = xzbuf + 12582912;                    // 6,291,456 f32
    uint32* dtvx = (uint32*)(ysum + 6291456);           // 25,165,824 u32 (bf16x2)
    float* FH    = (float*)(dtvx + 25165824);           // 3,145,728 f32
    float* Parr  = FH + 3145728;                        // 3,145,728 f32
    float* out   = (float*)d_out;

    float* hmod  = regB;
    float* dbl48 = regB;
    float* tok2  = regB;
    float* xz    = xzbuf;
    float* a1    = xzbuf;

    k_mods<<<18, 256, 0, stream>>>(c, adaln_w, adaln_b, mods);
    k_ln_mod<<<4096, 256, 0, stream>>>(x, mods, hmod);
    k_xz<<<2048, 256, 0, stream>>>(hmod, W_in, b_in, xz);
    k_conv_dbl<<<8192, 384, 0, stream>>>(xz, conv_w, conv_b, W_x, W_dt, b_dt,
                                         dbl48, dtvx);
    hipMemsetAsync(ysum, 0, (size_t)6291456 * sizeof(float), stream);
    k_scanA<<<12288, 256, 0, stream>>>(dtvx, dbl48, A_log, FH, Parr);
    k_scanB<<<384, 256, 0, stream>>>(FH, Parr);
    k_scanC<<<12288, 256, 0, stream>>>(dtvx, dbl48, FH, A_log, Dp, ysum);
    k_out_gemm<<<2048, 192, 0, stream>>>(ysum, xz, W_out, b_out, x, mods, tok2);
    k_mlp1<<<2048, 256, 0, stream>>>(tok2, mods, w1, b1, a1);
    k_mlp2<<<2048, 192, 0, stream>>>(a1, tok2, mods, w2, b2, out);
}

// Round 8
// 1352.235 us; speedup vs baseline: 5.1962x; 1.0378x over previous
//
#include <hip/hip_runtime.h>
#include <hip/hip_bf16.h>

// Problem constants
#define NB   4       // batch
#define CC   192     // d_model
#define LL   4096    // H*W
#define DI   384     // d_inner
#define DST  16      // d_state
#define DTR  12      // dt_rank
#define NC   32      // scan chunks
#define CL   128     // chunk length

typedef unsigned int uint32;
typedef unsigned short ushort16;

__device__ __forceinline__ float siluf(float x) {
    return x / (1.f + __expf(-x));
}
__device__ __forceinline__ float bf16lo(uint32 u) { return __uint_as_float(u << 16); }
__device__ __forceinline__ float bf16hi(uint32 u) { return __uint_as_float(u & 0xffff0000u); }

// scan-position l -> token position p, per direction
__device__ __forceinline__ int perm_pos(int dir, int l) {
    if (dir == 0) return l;
    if (dir == 1) return 4095 - l;
    if (dir == 2) return ((l & 63) << 6) | (l >> 6);
    int m = 4095 - l;
    return ((m & 63) << 6) | (m >> 6);
}

// K1: mods = silu(c) @ adaln_w + adaln_b   (4 x 1152)
__global__ void k_mods(const float* __restrict__ c, const float* __restrict__ w,
                       const float* __restrict__ bias, float* __restrict__ mods) {
    int idx = blockIdx.x * 256 + threadIdx.x;
    if (idx >= NB * 1152) return;
    int n = idx / 1152, j = idx % 1152;
    float acc = bias[j];
    for (int k = 0; k < CC; ++k) {
        acc = fmaf(siluf(c[n * CC + k]), w[k * 1152 + j], acc);
    }
    mods[idx] = acc;
}

// K2: hmod = modulate(LN(tokens), sh1, sc1)
__global__ void k_ln_mod(const float* __restrict__ x, const float* __restrict__ mods,
                         float* __restrict__ hmod) {
    int wave = blockIdx.x * 4 + (threadIdx.x >> 6);
    int lane = threadIdx.x & 63;
    int b = wave >> 12;
    int p = wave & 4095;
    float v0 = x[((size_t)(b * CC + lane) * LL) + p];
    float v1 = x[((size_t)(b * CC + lane + 64) * LL) + p];
    float v2 = x[((size_t)(b * CC + lane + 128) * LL) + p];
    float s = v0 + v1 + v2, sq = v0 * v0 + v1 * v1 + v2 * v2;
    #pragma unroll
    for (int o = 1; o < 64; o <<= 1) { s += __shfl_xor(s, o); sq += __shfl_xor(sq, o); }
    float mu = s * (1.f / 192.f);
    float var = sq * (1.f / 192.f) - mu * mu;
    float rs = rsqrtf(var + 1e-6f);
    const float* mb = mods + b * 1152;
    size_t base = ((size_t)(b * LL + p)) * CC;
    int c0 = lane, c1 = lane + 64, c2 = lane + 128;
    hmod[base + c0] = (v0 - mu) * rs * (1.f + mb[192 + c0]) + mb[c0];
    hmod[base + c1] = (v1 - mu) * rs * (1.f + mb[192 + c1]) + mb[c1];
    hmod[base + c2] = (v2 - mu) * rs * (1.f + mb[192 + c2]) + mb[c2];
}

// K3: xz = hmod @ W_in + b_in, 8 tokens/block, 256 threads
__global__ void k_xz(const float* __restrict__ hmod, const float* __restrict__ W_in,
                     const float* __restrict__ b_in, float* __restrict__ xz) {
    __shared__ float hs[8][CC];
    int tok0 = blockIdx.x * 8;       // 2048 blocks
    int t = threadIdx.x;             // 256
    for (int i = t; i < 8 * CC; i += 256) hs[i / CC][i % CC] = hmod[(size_t)tok0 * CC + i];
    __syncthreads();
    float b0 = b_in[t], b1 = b_in[t + 256], b2 = b_in[t + 512];
    float acc[8][3];
    #pragma unroll
    for (int i = 0; i < 8; ++i) { acc[i][0] = b0; acc[i][1] = b1; acc[i][2] = b2; }
    for (int k = 0; k < CC; ++k) {
        const float* wr = W_in + k * 768;
        float w0 = wr[t], w1 = wr[t + 256], w2 = wr[t + 512];
        #pragma unroll
        for (int i = 0; i < 8; ++i) {
            float hv = hs[i][k];
            acc[i][0] = fmaf(hv, w0, acc[i][0]);
            acc[i][1] = fmaf(hv, w1, acc[i][1]);
            acc[i][2] = fmaf(hv, w2, acc[i][2]);
        }
    }
    #pragma unroll
    for (int i = 0; i < 8; ++i) {
        float* orow = xz + ((size_t)tok0 + i) * 768;
        orow[t] = acc[i][0]; orow[t + 256] = acc[i][1]; orow[t + 512] = acc[i][2];
    }
}

// K4: 8 tokens/block, 384 threads. conv+silu -> xcs (LDS); dbl44 = xc@W_x -> dbl48
// (rows stored as [dt x12][B0 C0 B1 C1 ... B15 C15]);
// dt = softplus(dbl[:12]@W_dt + b_dt); pack (dtv, dtv*xv) bf16x2 -> dtvx[seq][l][384].
__global__ void k_conv_dbl(const float* __restrict__ xz, const float* __restrict__ conv_w,
                           const float* __restrict__ conv_b, const float* __restrict__ W_x,
                           const float* __restrict__ W_dt, const float* __restrict__ b_dt,
                           float* __restrict__ dbl48, uint32* __restrict__ dtvx) {
    __shared__ float xcs[8][DI];
    __shared__ float dbls[8][DTR];
    int blk = blockIdx.x;            // 8192 = seq*512 + lb
    int seq = blk >> 9;
    int lb = blk & 511;
    int l0 = lb * 8;
    int dir = seq >> 2, b = seq & 3;
    int t = threadIdx.x;             // 384
    // phase 1: conv + silu for 8 tokens, channel t, via 11-sample window
    {
        float cw0 = conv_w[t * 4 + 0], cw1 = conv_w[t * 4 + 1];
        float cw2 = conv_w[t * 4 + 2], cw3 = conv_w[t * 4 + 3];
        float cb = conv_b[t];
        float xwin[11];
        #pragma unroll
        for (int i = 0; i < 11; ++i) {
            int lk = l0 - 3 + i;
            xwin[i] = (lk >= 0)
                ? xz[((size_t)(b * LL + perm_pos(dir, lk))) * 768 + t] : 0.f;
        }
        #pragma unroll
        for (int i = 0; i < 8; ++i) {
            float acc = cb;
            acc = fmaf(cw0, xwin[i], acc);
            acc = fmaf(cw1, xwin[i + 1], acc);
            acc = fmaf(cw2, xwin[i + 2], acc);
            acc = fmaf(cw3, xwin[i + 3], acc);
            xcs[i][t] = siluf(acc);
        }
    }
    __syncthreads();
    // phase 2: dbl44 per token; 352 threads = 8 tokens x 44 outputs, K=384
    if (t < 352) {
        int i = t / 44, j = t - i * 44;
        float ps = 0.f;
        #pragma unroll 4
        for (int k = 0; k < DI; ++k) ps = fmaf(xcs[i][k], W_x[k * 44 + j], ps);
        if (j < DTR) dbls[i][j] = ps;
        // interleaved store: dt at [0:12); B_s at 12+2s; C_s at 13+2s
        int idx = (j < 12) ? j : ((j < 28) ? (12 + 2 * (j - 12)) : (13 + 2 * (j - 28)));
        dbl48[((size_t)(seq * LL) + l0 + i) * 48 + idx] = ps;
    }
    __syncthreads();
    // phase 3: dt for 8 tokens, channel t
    {
        float wdtc[DTR];
        #pragma unroll
        for (int r = 0; r < DTR; ++r) wdtc[r] = W_dt[r * DI + t];
        float bdt = b_dt[t];
        #pragma unroll
        for (int i = 0; i < 8; ++i) {
            float acc = bdt;
            #pragma unroll
            for (int r = 0; r < DTR; ++r) acc = fmaf(dbls[i][r], wdtc[r], acc);
            float sp = (acc > 15.f) ? acc : __logf(1.f + __expf(acc));
            sp = fmaxf(sp, 1e-12f);
            float xv = xcs[i][t];
            __hip_bfloat16 hv = __float2bfloat16(sp);
            __hip_bfloat16 hx = __float2bfloat16(sp * xv);
            uint32 pack = ((uint32)(*(ushort16*)&hx) << 16) | (uint32)(*(ushort16*)&hv);
            dtvx[((size_t)(seq * LL) + l0 + i) * DI + t] = pack;
        }
    }
}

// K5a: per-chunk local scan -> final state FH, decay product P
__global__ void k_scanA(const uint32* __restrict__ dtvx, const float* __restrict__ dbl48,
                        const float* __restrict__ A_log,
                        float* __restrict__ FH, float* __restrict__ Parr) {
    int blk = blockIdx.x;            // (seq*NC + c)*24 + gblk ; 12288 blocks
    int gblk = blk % 24;
    int sc = blk / 24;
    int c = sc & (NC - 1);
    int seq = sc / NC;
    int w = threadIdx.x >> 6, lane = threadIdx.x & 63;
    int g96 = gblk * 4 + w;
    int s = lane & 15, g = lane >> 4;
    int d = g96 * 4 + g;
    float a_s = -__expf(A_log[d * DST + s]);
    int l0 = c * CL;
    const uint32* pdt = dtvx + ((size_t)(seq * LL) + l0) * DI + d;
    const float* dbc = dbl48 + ((size_t)(seq * LL) + l0) * 48 + 12 + 2 * s;
    float h = 0.f, P = 1.f;
    #pragma unroll 8
    for (int l = 0; l < CL; ++l) {
        uint32 u = pdt[(size_t)l * DI];
        float dtv = bf16lo(u);
        float dtx = bf16hi(u);
        float Bv = dbc[l * 48];
        float dA = __expf(dtv * a_s);
        h = fmaf(h, dA, dtx * Bv);
        P *= dA;
    }
    size_t o = ((size_t)(seq * NC + c) * 96 + g96) * 64 + lane;
    FH[o] = h;
    Parr[o] = P;
}

// K5b: chunk-state prefix: Hin_c = H; H = F_c + P_c*H  (FH overwritten with Hin)
__global__ void k_scanB(float* __restrict__ FH, const float* __restrict__ Parr) {
    int wid = blockIdx.x * 4 + (threadIdx.x >> 6);   // 384 blocks -> 1536 waves
    int lane = threadIdx.x & 63;
    int seq = wid / 96, g96 = wid % 96;
    float H = 0.f;
    for (int c = 0; c < NC; ++c) {
        size_t o = ((size_t)(seq * NC + c) * 96 + g96) * 64 + lane;
        float F = FH[o], P = Parr[o];
        FH[o] = H;
        H = fmaf(P, H, F);
    }
}

// K5c: local scan seeded with Hin, emit raw y; atomicAdd into ysum[(b,p,d)].
// Tail-batched: lane s keeps the reduced sum of step (l&15)==s; every 16 steps
// all lanes finalize 16 outputs in parallel.
__global__ void k_scanC(const uint32* __restrict__ dtvx, const float* __restrict__ dbl48,
                        const float* __restrict__ FH,
                        const float* __restrict__ A_log, const float* __restrict__ Dp,
                        float* __restrict__ ysum) {
    int blk = blockIdx.x;
    int gblk = blk % 24;
    int sc = blk / 24;
    int c = sc & (NC - 1);
    int seq = sc / NC;
    int w = threadIdx.x >> 6, lane = threadIdx.x & 63;
    int g96 = gblk * 4 + w;
    int s = lane & 15, g = lane >> 4;
    int d = g96 * 4 + g;
    int dir = seq >> 2, b = seq & 3;
    float a_s = -__expf(A_log[d * DST + s]);
    float D_d = Dp[d];
    int l0 = c * CL;
    const uint32* pdt = dtvx + ((size_t)(seq * LL) + l0) * DI + d;
    const float* dbc = dbl48 + ((size_t)(seq * LL) + l0) * 48 + 12 + 2 * s;
    float* yb = ysum + (size_t)(b * LL) * DI + d;
    float h = FH[((size_t)(seq * NC + c) * 96 + g96) * 64 + lane];
    for (int grp = 0; grp < CL / 16; ++grp) {
        float ysv = 0.f;
        #pragma unroll
        for (int j = 0; j < 16; ++j) {
            int l = grp * 16 + j;
            uint32 u = pdt[(size_t)l * DI];
            float2 bc = *(const float2*)&dbc[l * 48];
            float dtv = bf16lo(u);
            float dtx = bf16hi(u);
            float dA = __expf(dtv * a_s);
            h = fmaf(h, dA, dtx * bc.x);
            float pr = h * bc.y;
            pr += __shfl_xor(pr, 1);
            pr += __shfl_xor(pr, 2);
            pr += __shfl_xor(pr, 4);
            pr += __shfl_xor(pr, 8);
            if (s == j) ysv = pr;          // compile-time j: cmp+cndmask
        }
        // batched tail: lane s finalizes step grp*16+s (u lines are L1-hot)
        int l = grp * 16 + s;
        uint32 u = pdt[(size_t)l * DI];
        float dtv = bf16lo(u);
        float dtx = bf16hi(u);
        float xv = dtx * __builtin_amdgcn_rcpf(dtv);   // dtv >= 1e-12 from k4
        float y = ysv + D_d * xv;
        int p = perm_pos(dir, l0 + l);
        atomicAdd(&yb[(size_t)p * DI], y);
    }
}

// K6: ys = ysum * 0.25*silu(z); tok2 = x + g1*(ys@W_out + b_out); 8 tok/block, 192 thr
__global__ void k_out_gemm(const float* __restrict__ ysum, const float* __restrict__ xz,
                           const float* __restrict__ W_out, const float* __restrict__ b_out,
                           const float* __restrict__ x, const float* __restrict__ mods,
                           float* __restrict__ tok2) {
    __shared__ float ys[8][DI];
    int tok0 = blockIdx.x * 8;       // 2048 blocks
    int b = tok0 >> 12;
    int p0 = tok0 & 4095;
    int t = threadIdx.x;             // 192
    for (int i = t; i < 8 * DI; i += 192) {
        int tok = i / DI, k = i % DI;
        float zv = xz[((size_t)tok0 + tok) * 768 + DI + k];
        ys[tok][k] = ysum[(size_t)tok0 * DI + i] * 0.25f * siluf(zv);
    }
    __syncthreads();
    float acc[8];
    #pragma unroll
    for (int i = 0; i < 8; ++i) acc[i] = 0.f;
    for (int k = 0; k < DI; ++k) {
        float wv = W_out[k * CC + t];
        #pragma unroll
        for (int i = 0; i < 8; ++i) acc[i] = fmaf(ys[i][k], wv, acc[i]);
    }
    float bo = b_out[t];
    float g1 = mods[b * 1152 + 384 + t];
    const float* xr = x + ((size_t)(b * CC + t)) * LL + p0;
    #pragma unroll
    for (int i = 0; i < 8; ++i) {
        tok2[((size_t)tok0 + i) * CC + t] = xr[i] + g1 * (acc[i] + bo);
    }
}

// K7: m = modulate(LN(tok2), sh2, sc2); a1 = gelu(m @ w1 + b1); 8 tokens/block, 256 thr
__global__ void k_mlp1(const float* __restrict__ tok2, const float* __restrict__ mods,
                       const float* __restrict__ w1, const float* __restrict__ b1,
                       float* __restrict__ a1) {
    __shared__ float ms[8][CC];
    int tok0 = blockIdx.x * 8;       // 2048 blocks
    int b = tok0 >> 12;
    int t = threadIdx.x;             // 256
    for (int i = t; i < 8 * CC; i += 256) ms[i / CC][i % CC] = tok2[(size_t)tok0 * CC + i];
    __syncthreads();
    {
        int i = t >> 5, ln = t & 31;
        float s = 0.f, sq = 0.f;
        for (int j = ln; j < CC; j += 32) { float v = ms[i][j]; s += v; sq += v * v; }
        #pragma unroll
        for (int o = 1; o < 32; o <<= 1) { s += __shfl_xor(s, o); sq += __shfl_xor(sq, o); }
        float mu = s * (1.f / 192.f);
        float var = sq * (1.f / 192.f) - mu * mu;
        float rs = rsqrtf(var + 1e-6f);
        const float* mb = mods + b * 1152;
        for (int j = ln; j < CC; j += 32) {
            ms[i][j] = (ms[i][j] - mu) * rs * (1.f + mb[768 + j]) + mb[576 + j];
        }
    }
    __syncthreads();
    float bb0 = b1[t], bb1 = b1[t + 256], bb2 = b1[t + 512];
    float acc[8][3];
    #pragma unroll
    for (int i = 0; i < 8; ++i) { acc[i][0] = bb0; acc[i][1] = bb1; acc[i][2] = bb2; }
    for (int k = 0; k < CC; ++k) {
        const float* wr = w1 + k * 768;
        float w0 = wr[t], wv1 = wr[t + 256], wv2 = wr[t + 512];
        #pragma unroll
        for (int i = 0; i < 8; ++i) {
            float mv = ms[i][k];
            acc[i][0] = fmaf(mv, w0, acc[i][0]);
            acc[i][1] = fmaf(mv, wv1, acc[i][1]);
            acc[i][2] = fmaf(mv, wv2, acc[i][2]);
        }
    }
    #pragma unroll
    for (int i = 0; i < 8; ++i) {
        float* orow = a1 + ((size_t)tok0 + i) * 768;
        #pragma unroll
        for (int r = 0; r < 3; ++r) {
            float u = acc[i][r];
            float inner = 0.7978845608028654f * (u + 0.044715f * u * u * u);
            float e = __expf(2.f * inner);
            float th = 1.f - 2.f / (e + 1.f);
            orow[t + 256 * r] = 0.5f * u * (1.f + th);
        }
    }
}

// K8: out = tok2 + g2 * (a1 @ w2 + b2), (b,C,h,w) layout; 8 tokens/block, 192 thr
__global__ void k_mlp2(const float* __restrict__ a1, const float* __restrict__ tok2,
                       const float* __restrict__ mods, const float* __restrict__ w2,
                       const float* __restrict__ b2, float* __restrict__ out) {
    __shared__ float as[8][768];
    int tok0 = blockIdx.x * 8;       // 2048 blocks
    int b = tok0 >> 12;
    int p0 = tok0 & 4095;
    int t = threadIdx.x;             // 192
    for (int i = t; i < 8 * 768; i += 192) as[i / 768][i % 768] = a1[(size_t)tok0 * 768 + i];
    __syncthreads();
    float acc[8];
    float bb = b2[t];
    #pragma unroll
    for (int i = 0; i < 8; ++i) acc[i] = bb;
    for (int k = 0; k < 768; ++k) {
        float wv = w2[k * CC + t];
        #pragma unroll
        for (int i = 0; i < 8; ++i) acc[i] = fmaf(as[i][k], wv, acc[i]);
    }
    float g2 = mods[b * 1152 + 960 + t];
    float* orow = out + ((size_t)(b * CC + t)) * LL + p0;
    #pragma unroll
    for (int i = 0; i < 8; ++i) {
        orow[i] = tok2[((size_t)tok0 + i) * CC + t] + g2 * acc[i];
    }
}

extern "C" void kernel_launch(void* const* d_in, const int* in_sizes, int n_in,
                              void* d_out, int out_size, void* d_ws, size_t ws_size,
                              hipStream_t stream) {
    const float* x       = (const float*)d_in[0];
    const float* c       = (const float*)d_in[1];
    const float* adaln_w = (const float*)d_in[2];
    const float* adaln_b = (const float*)d_in[3];
    const float* W_in    = (const float*)d_in[4];
    const float* b_in    = (const float*)d_in[5];
    const float* conv_w  = (const float*)d_in[6];
    const float* conv_b  = (const float*)d_in[7];
    const float* W_x     = (const float*)d_in[8];
    const float* W_dt    = (const float*)d_in[9];
    const float* b_dt    = (const float*)d_in[10];
    const float* A_log   = (const float*)d_in[11];
    const float* Dp      = (const float*)d_in[12];
    const float* W_out   = (const float*)d_in[13];
    const float* b_out   = (const float*)d_in[14];
    const float* w1      = (const float*)d_in[15];
    const float* b1      = (const float*)d_in[16];
    const float* w2      = (const float*)d_in[17];
    const float* b2      = (const float*)d_in[18];

    // workspace (~214 MB):
    //  regB (12.6MB): hmod (k2-k3) -> dbl48 (k4-scans) -> tok2 (k6-k8)
    //  xzbuf (50MB):  xz (k3-k6) -> a1 (k7-k8)
    //  ysum (25MB), dtvx (100MB), FH/Parr (12.6MB each)
    float* ws = (float*)d_ws;
    float* mods  = ws;                                  // 4,608
    float* regB  = ws + 4608;                           // 3,145,728 f32
    float* xzbuf = regB + 3145728;                      // 12,582,912 f32
    float* ysum  = xzbuf + 12582912;                    // 6,291,456 f32
    uint32* dtvx = (uint32*)(ysum + 6291456);           // 25,165,824 u32 (bf16x2)
    float* FH    = (float*)(dtvx + 25165824);           // 3,145,728 f32
    float* Parr  = FH + 3145728;                        // 3,145,728 f32
    float* out   = (float*)d_out;

    float* hmod  = regB;
    float* dbl48 = regB;
    float* tok2  = regB;
    float* xz    = xzbuf;
    float* a1    = xzbuf;

    k_mods<<<18, 256, 0, stream>>>(c, adaln_w, adaln_b, mods);
    k_ln_mod<<<4096, 256, 0, stream>>>(x, mods, hmod);
    k_xz<<<2048, 256, 0, stream>>>(hmod, W_in, b_in, xz);
    k_conv_dbl<<<8192, 384, 0, stream>>>(xz, conv_w, conv_b, W_x, W_dt, b_dt,
                                         dbl48, dtvx);
    hipMemsetAsync(ysum, 0, (size_t)6291456 * sizeof(float), stream);
    k_scanA<<<12288, 256, 0, stream>>>(dtvx, dbl48, A_log, FH, Parr);
    k_scanB<<<384, 256, 0, stream>>>(FH, Parr);
    k_scanC<<<12288, 256, 0, stream>>>(dtvx, dbl48, FH, A_log, Dp, ysum);
    k_out_gemm<<<2048, 192, 0, stream>>>(ysum, xz, W_out, b_out, x, mods, tok2);
    k_mlp1<<<2048, 256, 0, stream>>>(tok2, mods, w1, b1, a1);
    k_mlp2<<<2048, 192, 0, stream>>>(a1, tok2, mods, w2, b2, out);
}

// Round 9
// 969.960 us; speedup vs baseline: 7.2441x; 1.3941x over previous
//
#include <hip/hip_runtime.h>
#include <hip/hip_bf16.h>

// Problem constants
#define NB   4       // batch
#define CC   192     // d_model
#define LL   4096    // H*W
#define DI   384     // d_inner
#define DST  16      // d_state
#define DTR  12      // dt_rank
#define NC   64      // scan chunks
#define CL   64      // chunk length

typedef unsigned int uint32;
typedef unsigned short ushort16;

__device__ __forceinline__ float siluf(float x) {
    return x / (1.f + __expf(-x));
}
__device__ __forceinline__ float bf16lo(uint32 u) { return __uint_as_float(u << 16); }
__device__ __forceinline__ float bf16hi(uint32 u) { return __uint_as_float(u & 0xffff0000u); }

// scan-position l -> token position p, per direction
__device__ __forceinline__ int perm_pos(int dir, int l) {
    if (dir == 0) return l;
    if (dir == 1) return 4095 - l;
    if (dir == 2) return ((l & 63) << 6) | (l >> 6);
    int m = 4095 - l;
    return ((m & 63) << 6) | (m >> 6);
}

// K1: mods = silu(c) @ adaln_w + adaln_b   (4 x 1152)
__global__ void k_mods(const float* __restrict__ c, const float* __restrict__ w,
                       const float* __restrict__ bias, float* __restrict__ mods) {
    int idx = blockIdx.x * 256 + threadIdx.x;
    if (idx >= NB * 1152) return;
    int n = idx / 1152, j = idx % 1152;
    float acc = bias[j];
    for (int k = 0; k < CC; ++k) {
        acc = fmaf(siluf(c[n * CC + k]), w[k * 1152 + j], acc);
    }
    mods[idx] = acc;
}

// K2: hmod = modulate(LN(tokens), sh1, sc1)
__global__ void k_ln_mod(const float* __restrict__ x, const float* __restrict__ mods,
                         float* __restrict__ hmod) {
    int wave = blockIdx.x * 4 + (threadIdx.x >> 6);
    int lane = threadIdx.x & 63;
    int b = wave >> 12;
    int p = wave & 4095;
    float v0 = x[((size_t)(b * CC + lane) * LL) + p];
    float v1 = x[((size_t)(b * CC + lane + 64) * LL) + p];
    float v2 = x[((size_t)(b * CC + lane + 128) * LL) + p];
    float s = v0 + v1 + v2, sq = v0 * v0 + v1 * v1 + v2 * v2;
    #pragma unroll
    for (int o = 1; o < 64; o <<= 1) { s += __shfl_xor(s, o); sq += __shfl_xor(sq, o); }
    float mu = s * (1.f / 192.f);
    float var = sq * (1.f / 192.f) - mu * mu;
    float rs = rsqrtf(var + 1e-6f);
    const float* mb = mods + b * 1152;
    size_t base = ((size_t)(b * LL + p)) * CC;
    int c0 = lane, c1 = lane + 64, c2 = lane + 128;
    hmod[base + c0] = (v0 - mu) * rs * (1.f + mb[192 + c0]) + mb[c0];
    hmod[base + c1] = (v1 - mu) * rs * (1.f + mb[192 + c1]) + mb[c1];
    hmod[base + c2] = (v2 - mu) * rs * (1.f + mb[192 + c2]) + mb[c2];
}

// K3: xz = hmod @ W_in + b_in, 8 tokens/block, 256 threads
__global__ void k_xz(const float* __restrict__ hmod, const float* __restrict__ W_in,
                     const float* __restrict__ b_in, float* __restrict__ xz) {
    __shared__ float hs[8][CC];
    int tok0 = blockIdx.x * 8;       // 2048 blocks
    int t = threadIdx.x;             // 256
    for (int i = t; i < 8 * CC; i += 256) hs[i / CC][i % CC] = hmod[(size_t)tok0 * CC + i];
    __syncthreads();
    float b0 = b_in[t], b1 = b_in[t + 256], b2 = b_in[t + 512];
    float acc[8][3];
    #pragma unroll
    for (int i = 0; i < 8; ++i) { acc[i][0] = b0; acc[i][1] = b1; acc[i][2] = b2; }
    for (int k = 0; k < CC; ++k) {
        const float* wr = W_in + k * 768;
        float w0 = wr[t], w1 = wr[t + 256], w2 = wr[t + 512];
        #pragma unroll
        for (int i = 0; i < 8; ++i) {
            float hv = hs[i][k];
            acc[i][0] = fmaf(hv, w0, acc[i][0]);
            acc[i][1] = fmaf(hv, w1, acc[i][1]);
            acc[i][2] = fmaf(hv, w2, acc[i][2]);
        }
    }
    #pragma unroll
    for (int i = 0; i < 8; ++i) {
        float* orow = xz + ((size_t)tok0 + i) * 768;
        orow[t] = acc[i][0]; orow[t + 256] = acc[i][1]; orow[t + 512] = acc[i][2];
    }
}

// K4: 8 tokens/block, 384 threads. conv+silu -> xcs (LDS); dbl44 = xc@W_x -> dbl48
// (rows stored as [dt x12][B0 C0 B1 C1 ... B15 C15]);
// dt = softplus(dbl[:12]@W_dt + b_dt); pack (dtv, dtv*xv) bf16x2 -> dtvx[seq][l][384].
__global__ void k_conv_dbl(const float* __restrict__ xz, const float* __restrict__ conv_w,
                           const float* __restrict__ conv_b, const float* __restrict__ W_x,
                           const float* __restrict__ W_dt, const float* __restrict__ b_dt,
                           float* __restrict__ dbl48, uint32* __restrict__ dtvx) {
    __shared__ float xcs[8][DI];
    __shared__ float dbls[8][DTR];
    int blk = blockIdx.x;            // 8192 = seq*512 + lb
    int seq = blk >> 9;
    int lb = blk & 511;
    int l0 = lb * 8;
    int dir = seq >> 2, b = seq & 3;
    int t = threadIdx.x;             // 384
    // phase 1: conv + silu for 8 tokens, channel t, via 11-sample window
    {
        float cw0 = conv_w[t * 4 + 0], cw1 = conv_w[t * 4 + 1];
        float cw2 = conv_w[t * 4 + 2], cw3 = conv_w[t * 4 + 3];
        float cb = conv_b[t];
        float xwin[11];
        #pragma unroll
        for (int i = 0; i < 11; ++i) {
            int lk = l0 - 3 + i;
            xwin[i] = (lk >= 0)
                ? xz[((size_t)(b * LL + perm_pos(dir, lk))) * 768 + t] : 0.f;
        }
        #pragma unroll
        for (int i = 0; i < 8; ++i) {
            float acc = cb;
            acc = fmaf(cw0, xwin[i], acc);
            acc = fmaf(cw1, xwin[i + 1], acc);
            acc = fmaf(cw2, xwin[i + 2], acc);
            acc = fmaf(cw3, xwin[i + 3], acc);
            xcs[i][t] = siluf(acc);
        }
    }
    __syncthreads();
    // phase 2: dbl44 per token; 352 threads = 8 tokens x 44 outputs, K=384
    if (t < 352) {
        int i = t / 44, j = t - i * 44;
        float ps = 0.f;
        #pragma unroll 4
        for (int k = 0; k < DI; ++k) ps = fmaf(xcs[i][k], W_x[k * 44 + j], ps);
        if (j < DTR) dbls[i][j] = ps;
        // interleaved store: dt at [0:12); B_s at 12+2s; C_s at 13+2s
        int idx = (j < 12) ? j : ((j < 28) ? (12 + 2 * (j - 12)) : (13 + 2 * (j - 28)));
        dbl48[((size_t)(seq * LL) + l0 + i) * 48 + idx] = ps;
    }
    __syncthreads();
    // phase 3: dt for 8 tokens, channel t
    {
        float wdtc[DTR];
        #pragma unroll
        for (int r = 0; r < DTR; ++r) wdtc[r] = W_dt[r * DI + t];
        float bdt = b_dt[t];
        #pragma unroll
        for (int i = 0; i < 8; ++i) {
            float acc = bdt;
            #pragma unroll
            for (int r = 0; r < DTR; ++r) acc = fmaf(dbls[i][r], wdtc[r], acc);
            float sp = (acc > 15.f) ? acc : __logf(1.f + __expf(acc));
            sp = fmaxf(sp, 1e-12f);
            float xv = xcs[i][t];
            __hip_bfloat16 hv = __float2bfloat16(sp);
            __hip_bfloat16 hx = __float2bfloat16(sp * xv);
            uint32 pack = ((uint32)(*(ushort16*)&hx) << 16) | (uint32)(*(ushort16*)&hv);
            dtvx[((size_t)(seq * LL) + l0 + i) * DI + t] = pack;
        }
    }
}

// K5a: per-chunk local scan, 16 states per THREAD (no shuffles).
// Block = (seq, chunk), 384 threads (one per channel).
// Stores h[16], P[16] to FH/Parr in [sc][s][384] layout (d-coalesced).
__global__ void k_scanA(const uint32* __restrict__ dtvx, const float* __restrict__ dbl48,
                        const float* __restrict__ A_log,
                        float* __restrict__ FH, float* __restrict__ Parr) {
    int blk = blockIdx.x;            // 1024 = seq*NC + c
    int seq = blk >> 6;
    int c = blk & (NC - 1);
    int d = threadIdx.x;             // 384
    float a_s[DST], h[DST], P[DST];
    {
        const float4* Aq = (const float4*)(A_log + d * DST);
        #pragma unroll
        for (int i = 0; i < 4; ++i) {
            float4 v = Aq[i];
            a_s[4 * i + 0] = -__expf(v.x);
            a_s[4 * i + 1] = -__expf(v.y);
            a_s[4 * i + 2] = -__expf(v.z);
            a_s[4 * i + 3] = -__expf(v.w);
        }
    }
    #pragma unroll
    for (int s = 0; s < DST; ++s) { h[s] = 0.f; P[s] = 1.f; }
    int l0 = c * CL;
    const uint32* pdt = dtvx + ((size_t)(seq * LL) + l0) * DI + d;
    const float* dbc = dbl48 + ((size_t)(seq * LL) + l0) * 48 + 12;
    #pragma unroll 2
    for (int l = 0; l < CL; ++l) {
        uint32 u = pdt[(size_t)l * DI];
        float dtv = bf16lo(u);
        float dtx = bf16hi(u);
        const float4* q = (const float4*)(dbc + l * 48);
        #pragma unroll
        for (int i = 0; i < 8; ++i) {
            float4 v = q[i];                       // B2i C2i B2i+1 C2i+1
            float dA0 = __expf(dtv * a_s[2 * i]);
            h[2 * i] = fmaf(h[2 * i], dA0, dtx * v.x);
            P[2 * i] *= dA0;
            float dA1 = __expf(dtv * a_s[2 * i + 1]);
            h[2 * i + 1] = fmaf(h[2 * i + 1], dA1, dtx * v.z);
            P[2 * i + 1] *= dA1;
        }
    }
    // store: FH[((sc)*16 + s)*384 + d]
    size_t base = ((size_t)blk * DST) * 384 + d;
    #pragma unroll
    for (int s = 0; s < DST; ++s) {
        FH[base + (size_t)s * 384] = h[s];
        Parr[base + (size_t)s * 384] = P[s];
    }
}

// K5b: chunk-state prefix: Hin_c = H; H = F_c + P_c*H  (FH overwritten with Hin)
// thread = (seq, s, d); reads across c are d-coalesced.
__global__ void k_scanB(float* __restrict__ FH, const float* __restrict__ Parr) {
    int tid = blockIdx.x * 256 + threadIdx.x;   // 98304 = 16*16*384
    int seq = tid / 6144;
    int r = tid - seq * 6144;                   // s*384 + d
    float H = 0.f;
    size_t stride = (size_t)DST * 384;
    size_t o = ((size_t)seq * NC * DST) * 384 + r;
    for (int c = 0; c < NC; ++c) {
        float F = FH[o], P = Parr[o];
        FH[o] = H;
        H = fmaf(P, H, F);
        o += stride;
    }
}

// K5c: local scan seeded with Hin, 16 states per thread; per-step y for channel d;
// coalesced atomicAdd of the whole 384-channel row into ysum[b][p][.].
__global__ void k_scanC(const uint32* __restrict__ dtvx, const float* __restrict__ dbl48,
                        const float* __restrict__ FH,
                        const float* __restrict__ A_log, const float* __restrict__ Dp,
                        float* __restrict__ ysum) {
    int blk = blockIdx.x;            // 1024 = seq*NC + c
    int seq = blk >> 6;
    int c = blk & (NC - 1);
    int d = threadIdx.x;             // 384
    int dir = seq >> 2, b = seq & 3;
    float a_s[DST], h[DST];
    {
        const float4* Aq = (const float4*)(A_log + d * DST);
        #pragma unroll
        for (int i = 0; i < 4; ++i) {
            float4 v = Aq[i];
            a_s[4 * i + 0] = -__expf(v.x);
            a_s[4 * i + 1] = -__expf(v.y);
            a_s[4 * i + 2] = -__expf(v.z);
            a_s[4 * i + 3] = -__expf(v.w);
        }
    }
    {
        size_t base = ((size_t)blk * DST) * 384 + d;
        #pragma unroll
        for (int s = 0; s < DST; ++s) h[s] = FH[base + (size_t)s * 384];
    }
    float D_d = Dp[d];
    int l0 = c * CL;
    const uint32* pdt = dtvx + ((size_t)(seq * LL) + l0) * DI + d;
    const float* dbc = dbl48 + ((size_t)(seq * LL) + l0) * 48 + 12;
    float* yb = ysum + (size_t)(b * LL) * DI + d;
    #pragma unroll 2
    for (int l = 0; l < CL; ++l) {
        uint32 u = pdt[(size_t)l * DI];
        float dtv = bf16lo(u);
        float dtx = bf16hi(u);
        const float4* q = (const float4*)(dbc + l * 48);
        float y = 0.f;
        #pragma unroll
        for (int i = 0; i < 8; ++i) {
            float4 v = q[i];                       // B2i C2i B2i+1 C2i+1
            float dA0 = __expf(dtv * a_s[2 * i]);
            h[2 * i] = fmaf(h[2 * i], dA0, dtx * v.x);
            y = fmaf(h[2 * i], v.y, y);
            float dA1 = __expf(dtv * a_s[2 * i + 1]);
            h[2 * i + 1] = fmaf(h[2 * i + 1], dA1, dtx * v.z);
            y = fmaf(h[2 * i + 1], v.w, y);
        }
        float xv = dtx * __builtin_amdgcn_rcpf(dtv);   // dtv >= 1e-12 from k4
        y = fmaf(D_d, xv, y);
        int p = perm_pos(dir, l0 + l);
        atomicAdd(&yb[(size_t)p * DI], y);
    }
}

// K6: ys = ysum * 0.25*silu(z); tok2 = x + g1*(ys@W_out + b_out); 8 tok/block, 192 thr
__global__ void k_out_gemm(const float* __restrict__ ysum, const float* __restrict__ xz,
                           const float* __restrict__ W_out, const float* __restrict__ b_out,
                           const float* __restrict__ x, const float* __restrict__ mods,
                           float* __restrict__ tok2) {
    __shared__ float ys[8][DI];
    int tok0 = blockIdx.x * 8;       // 2048 blocks
    int b = tok0 >> 12;
    int p0 = tok0 & 4095;
    int t = threadIdx.x;             // 192
    for (int i = t; i < 8 * DI; i += 192) {
        int tok = i / DI, k = i % DI;
        float zv = xz[((size_t)tok0 + tok) * 768 + DI + k];
        ys[tok][k] = ysum[(size_t)tok0 * DI + i] * 0.25f * siluf(zv);
    }
    __syncthreads();
    float acc[8];
    #pragma unroll
    for (int i = 0; i < 8; ++i) acc[i] = 0.f;
    for (int k = 0; k < DI; ++k) {
        float wv = W_out[k * CC + t];
        #pragma unroll
        for (int i = 0; i < 8; ++i) acc[i] = fmaf(ys[i][k], wv, acc[i]);
    }
    float bo = b_out[t];
    float g1 = mods[b * 1152 + 384 + t];
    const float* xr = x + ((size_t)(b * CC + t)) * LL + p0;
    #pragma unroll
    for (int i = 0; i < 8; ++i) {
        tok2[((size_t)tok0 + i) * CC + t] = xr[i] + g1 * (acc[i] + bo);
    }
}

// K7: m = modulate(LN(tok2), sh2, sc2); a1 = gelu(m @ w1 + b1); 8 tokens/block, 256 thr
__global__ void k_mlp1(const float* __restrict__ tok2, const float* __restrict__ mods,
                       const float* __restrict__ w1, const float* __restrict__ b1,
                       float* __restrict__ a1) {
    __shared__ float ms[8][CC];
    int tok0 = blockIdx.x * 8;       // 2048 blocks
    int b = tok0 >> 12;
    int t = threadIdx.x;             // 256
    for (int i = t; i < 8 * CC; i += 256) ms[i / CC][i % CC] = tok2[(size_t)tok0 * CC + i];
    __syncthreads();
    {
        int i = t >> 5, ln = t & 31;
        float s = 0.f, sq = 0.f;
        for (int j = ln; j < CC; j += 32) { float v = ms[i][j]; s += v; sq += v * v; }
        #pragma unroll
        for (int o = 1; o < 32; o <<= 1) { s += __shfl_xor(s, o); sq += __shfl_xor(sq, o); }
        float mu = s * (1.f / 192.f);
        float var = sq * (1.f / 192.f) - mu * mu;
        float rs = rsqrtf(var + 1e-6f);
        const float* mb = mods + b * 1152;
        for (int j = ln; j < CC; j += 32) {
            ms[i][j] = (ms[i][j] - mu) * rs * (1.f + mb[768 + j]) + mb[576 + j];
        }
    }
    __syncthreads();
    float bb0 = b1[t], bb1 = b1[t + 256], bb2 = b1[t + 512];
    float acc[8][3];
    #pragma unroll
    for (int i = 0; i < 8; ++i) { acc[i][0] = bb0; acc[i][1] = bb1; acc[i][2] = bb2; }
    for (int k = 0; k < CC; ++k) {
        const float* wr = w1 + k * 768;
        float w0 = wr[t], wv1 = wr[t + 256], wv2 = wr[t + 512];
        #pragma unroll
        for (int i = 0; i < 8; ++i) {
            float mv = ms[i][k];
            acc[i][0] = fmaf(mv, w0, acc[i][0]);
            acc[i][1] = fmaf(mv, wv1, acc[i][1]);
            acc[i][2] = fmaf(mv, wv2, acc[i][2]);
        }
    }
    #pragma unroll
    for (int i = 0; i < 8; ++i) {
        float* orow = a1 + ((size_t)tok0 + i) * 768;
        #pragma unroll
        for (int r = 0; r < 3; ++r) {
            float u = acc[i][r];
            float inner = 0.7978845608028654f * (u + 0.044715f * u * u * u);
            float e = __expf(2.f * inner);
            float th = 1.f - 2.f / (e + 1.f);
            orow[t + 256 * r] = 0.5f * u * (1.f + th);
        }
    }
}

// K8: out = tok2 + g2 * (a1 @ w2 + b2), (b,C,h,w) layout; 8 tokens/block, 192 thr
__global__ void k_mlp2(const float* __restrict__ a1, const float* __restrict__ tok2,
                       const float* __restrict__ mods, const float* __restrict__ w2,
                       const float* __restrict__ b2, float* __restrict__ out) {
    __shared__ float as[8][768];
    int tok0 = blockIdx.x * 8;       // 2048 blocks
    int b = tok0 >> 12;
    int p0 = tok0 & 4095;
    int t = threadIdx.x;             // 192
    for (int i = t; i < 8 * 768; i += 192) as[i / 768][i % 768] = a1[(size_t)tok0 * 768 + i];
    __syncthreads();
    float acc[8];
    float bb = b2[t];
    #pragma unroll
    for (int i = 0; i < 8; ++i) acc[i] = bb;
    for (int k = 0; k < 768; ++k) {
        float wv = w2[k * CC + t];
        #pragma unroll
        for (int i = 0; i < 8; ++i) acc[i] = fmaf(as[i][k], wv, acc[i]);
    }
    float g2 = mods[b * 1152 + 960 + t];
    float* orow = out + ((size_t)(b * CC + t)) * LL + p0;
    #pragma unroll
    for (int i = 0; i < 8; ++i) {
        orow[i] = tok2[((size_t)tok0 + i) * CC + t] + g2 * acc[i];
    }
}

extern "C" void kernel_launch(void* const* d_in, const int* in_sizes, int n_in,
                              void* d_out, int out_size, void* d_ws, size_t ws_size,
                              hipStream_t stream) {
    const float* x       = (const float*)d_in[0];
    const float* c       = (const float*)d_in[1];
    const float* adaln_w = (const float*)d_in[2];
    const float* adaln_b = (const float*)d_in[3];
    const float* W_in    = (const float*)d_in[4];
    const float* b_in    = (const float*)d_in[5];
    const float* conv_w  = (const float*)d_in[6];
    const float* conv_b  = (const float*)d_in[7];
    const float* W_x     = (const float*)d_in[8];
    const float* W_dt    = (const float*)d_in[9];
    const float* b_dt    = (const float*)d_in[10];
    const float* A_log   = (const float*)d_in[11];
    const float* Dp      = (const float*)d_in[12];
    const float* W_out   = (const float*)d_in[13];
    const float* b_out   = (const float*)d_in[14];
    const float* w1      = (const float*)d_in[15];
    const float* b1      = (const float*)d_in[16];
    const float* w2      = (const float*)d_in[17];
    const float* b2      = (const float*)d_in[18];

    // workspace (~238 MB):
    //  regB (12.6MB): hmod (k2-k3) -> dbl48 (k4-scans) -> tok2 (k6-k8)
    //  xzbuf (50MB):  xz (k3-k6) -> a1 (k7-k8)
    //  ysum (25MB), dtvx (100MB), FH/Parr (25MB each; [sc][s][384] layout)
    float* ws = (float*)d_ws;
    float* mods  = ws;                                  // 4,608
    float* regB  = ws + 4608;                           // 3,145,728 f32
    float* xzbuf = regB + 3145728;                      // 12,582,912 f32
    float* ysum  = xzbuf + 12582912;                    // 6,291,456 f32
    uint32* dtvx = (uint32*)(ysum + 6291456);           // 25,165,824 u32 (bf16x2)
    float* FH    = (float*)(dtvx + 25165824);           // 6,291,456 f32
    float* Parr  = FH + 6291456;                        // 6,291,456 f32
    float* out   = (float*)d_out;

    float* hmod  = regB;
    float* dbl48 = regB;
    float* tok2  = regB;
    float* xz    = xzbuf;
    float* a1    = xzbuf;

    k_mods<<<18, 256, 0, stream>>>(c, adaln_w, adaln_b, mods);
    k_ln_mod<<<4096, 256, 0, stream>>>(x, mods, hmod);
    k_xz<<<2048, 256, 0, stream>>>(hmod, W_in, b_in, xz);
    k_conv_dbl<<<8192, 384, 0, stream>>>(xz, conv_w, conv_b, W_x, W_dt, b_dt,
                                         dbl48, dtvx);
    hipMemsetAsync(ysum, 0, (size_t)6291456 * sizeof(float), stream);
    k_scanA<<<1024, 384, 0, stream>>>(dtvx, dbl48, A_log, FH, Parr);
    k_scanB<<<384, 256, 0, stream>>>(FH, Parr);
    k_scanC<<<1024, 384, 0, stream>>>(dtvx, dbl48, FH, A_log, Dp, ysum);
    k_out_gemm<<<2048, 192, 0, stream>>>(ysum, xz, W_out, b_out, x, mods, tok2);
    k_mlp1<<<2048, 256, 0, stream>>>(tok2, mods, w1, b1, a1);
    k_mlp2<<<2048, 192, 0, stream>>>(a1, tok2, mods, w2, b2, out);
}